// Round 11
// baseline (123.500 us; speedup 1.0000x reference)
//
#include <hip/hip_runtime.h>
#include <hip/hip_bf16.h>
#include <math.h>

// MotionFormerBlock: bf16 MFMA GEMMs + swapped-operand MFMA flash attn.
// 8 dispatches. B=8, N=1024, DIM=256, MDIM=128, H=8, HD=32, HID=1024.
#define C_DIM 256
#define N_PTS 1024
#define H_N 8
#define MDIM_N 128
#define HID_N 1024
#define EPSV 1e-5f
#define R_TOT 8192
#define CN 262144               // C_DIM * N_PTS

typedef __bf16 bf16x8 __attribute__((ext_vector_type(8)));
typedef __bf16 bf16x4 __attribute__((ext_vector_type(4)));
typedef float f32x4 __attribute__((ext_vector_type(4)));

// softmax scale * log2(e): 32^-0.5 * 1.4426950408889634
#define QSCALE 0.25503482f

__device__ inline unsigned short bfu(float f) {
  union { __bf16 h; unsigned short u; } c;
  c.h = (__bf16)f;
  return c.u;
}

// ---------------------------------------------------- prep: wcvt + cet + bn1
// blocks [0,784): weight fp32->bf16; [784,1040): ceh->vt rows 32..47;
// [1040,1296): BN1 stats.
__global__ __launch_bounds__(256)
void prep_k(const float* __restrict__ s0, const float* __restrict__ s1,
            const float* __restrict__ s2, const float* __restrict__ s3,
            const float* __restrict__ s4, const float* __restrict__ s5,
            __bf16* d0, __bf16* d1, __bf16* d2, __bf16* d3, __bf16* d4,
            __bf16* d5, const float* __restrict__ cor,
            const float* __restrict__ cw, __bf16* __restrict__ vt,
            const float* __restrict__ x, const float* __restrict__ g1,
            const float* __restrict__ b1, float* __restrict__ st) {
  int blk = blockIdx.x;
  int t = threadIdx.x;
  if (blk < 784) {
    int i = blk * 256 + t;
    const float* s; __bf16* d; int off;
    if      (i <  16384) { s = s0; d = d0; off = 0; }
    else if (i <  49152) { s = s1; d = d1; off = 16384; }
    else if (i <  65536) { s = s2; d = d2; off = 49152; }
    else if (i <  69632) { s = s3; d = d3; off = 65536; }
    else if (i < 135168) { s = s4; d = d4; off = 69632; }
    else                 { s = s5; d = d5; off = 135168; }
    int j = i - off;
    float4 v = ((const float4*)s)[j];
    ushort4 u;
    u.x = bfu(v.x); u.y = bfu(v.y); u.z = bfu(v.z); u.w = bfu(v.w);
    ((ushort4*)d)[j] = u;
  } else if (blk < 1040) {
    __shared__ float cs[768];
    int j = blk - 784;
    int bh = j & 63, b = bh >> 3, h = bh & 7;
    int n0 = (j >> 6) * 256;
    for (int i = t; i < 768; i += 256)
      cs[i] = cor[(size_t)(b * N_PTS + n0) * 3 + i];
    __syncthreads();
    int md = t >> 4, ns = (t & 15) * 16;
    float w0 = cw[(h * 16 + md) * 3 + 0];
    float w1 = cw[(h * 16 + md) * 3 + 1];
    float w2 = cw[(h * 16 + md) * 3 + 2];
    __bf16* dst = &vt[((size_t)bh * 48 + 32 + md) * 1024 + n0 + ns];
#pragma unroll
    for (int g2 = 0; g2 < 4; ++g2) {
      ushort4 u;
      float v0 = cs[(ns + g2 * 4 + 0) * 3] * w0 + cs[(ns + g2 * 4 + 0) * 3 + 1] * w1 + cs[(ns + g2 * 4 + 0) * 3 + 2] * w2;
      float v1 = cs[(ns + g2 * 4 + 1) * 3] * w0 + cs[(ns + g2 * 4 + 1) * 3 + 1] * w1 + cs[(ns + g2 * 4 + 1) * 3 + 2] * w2;
      float v2 = cs[(ns + g2 * 4 + 2) * 3] * w0 + cs[(ns + g2 * 4 + 2) * 3 + 1] * w1 + cs[(ns + g2 * 4 + 2) * 3 + 2] * w2;
      float v3 = cs[(ns + g2 * 4 + 3) * 3] * w0 + cs[(ns + g2 * 4 + 3) * 3 + 1] * w1 + cs[(ns + g2 * 4 + 3) * 3 + 2] * w2;
      u.x = bfu(v0); u.y = bfu(v1); u.z = bfu(v2); u.w = bfu(v3);
      *(ushort4*)&dst[g2 * 4] = u;
    }
  } else {
    __shared__ float ss[256], sq[256];
    int c = blk - 1040;
    float s = 0.f, q = 0.f;
    for (int i = 0; i < 32; ++i) {
      int idx = t + i * 256;
      int b = idx >> 10, n = idx & 1023;
      float v = x[(size_t)b * CN + (size_t)c * N_PTS + n];
      s += v; q += v * v;
    }
    ss[t] = s; sq[t] = q;
    __syncthreads();
    for (int off = 128; off > 0; off >>= 1) {
      if (t < off) { ss[t] += ss[t + off]; sq[t] += sq[t + off]; }
      __syncthreads();
    }
    if (t == 0) {
      float mean = ss[0] * (1.f / 8192.f);
      float var  = sq[0] * (1.f / 8192.f) - mean * mean;
      float sc   = g1[c] * rsqrtf(var + EPSV);
      st[c]          = sc;
      st[C_DIM + c]  = b1[c] - mean * sc;
    }
  }
}

// ------------------------------------------- normalize + transpose (bf16 only)
__global__ __launch_bounds__(256)
void norm1_t_k(const float* __restrict__ x, const float* __restrict__ st,
               __bf16* __restrict__ xnb) {
  __shared__ float tile[32][33];
  int c0 = blockIdx.x * 32, n0 = blockIdx.y * 32, b = blockIdx.z;
  int tx = threadIdx.x, ty = threadIdx.y;
#pragma unroll
  for (int k = 0; k < 4; ++k) {
    int ci = ty + k * 8;
    int c = c0 + ci;
    float v = x[(size_t)b * CN + (size_t)c * N_PTS + n0 + tx];
    tile[ci][tx] = v * st[c] + st[C_DIM + c];
  }
  __syncthreads();
#pragma unroll
  for (int k = 0; k < 4; ++k) {
    int ni = ty + k * 8;
    xnb[((size_t)(b * N_PTS + n0 + ni)) * C_DIM + c0 + tx] =
        (__bf16)tile[tx][ni];
  }
}

// ---------------------------------------------------------------- MFMA attention
// 8 waves x 16 q-rows (512 thr), one (b,h) per blockIdx.x.
// SWAPPED operands: S^T = mfma(K, Q) -> lane owns full row q=l15;
// softmax in-register (+2 shfl); O^T = mfma(V'^T, P) -> stats stay on-lane.
__global__ __launch_bounds__(512)
void attn_k(const __bf16* __restrict__ qb, const __bf16* __restrict__ kb,
            const __bf16* __restrict__ vt, const float* __restrict__ cor,
            const float* __restrict__ cw, __bf16* __restrict__ av,
            __bf16* __restrict__ dmc) {
  __shared__ __bf16 KsV[2][64][40];
  __shared__ __bf16 VtV[2][48][72];
  __shared__ __bf16 Pbuf[8][16][72];

  int bh = blockIdx.x; int b = bh >> 3, h = bh & 7;
  int t = threadIdx.x;
  int w = t >> 6, lane = t & 63;
  int l15 = lane & 15, g = lane >> 4;

  int nloc0 = blockIdx.y * 128 + w * 16;
  bf16x8 aq =
      *(const bf16x8*)&qb[((size_t)bh * N_PTS + nloc0 + l15) * 32 + g * 8];

  const __bf16* ksrc = kb + (size_t)bh * N_PTS * 32;
  const __bf16* vsrc = vt + (size_t)bh * 48 * N_PTS;
  int u = t - 256;
  int vdv = u >> 3, vkg = u & 7;

  float mrun = -1e30f, lrun = 0.f;
  f32x4 acco[3];
#pragma unroll
  for (int mt = 0; mt < 3; ++mt) acco[mt] = (f32x4){0.f, 0.f, 0.f, 0.f};

  if (t < 256) {
    *(uint4*)&KsV[0][t >> 2][(t & 3) * 8] = *(const uint4*)&ksrc[t * 8];
  } else {
    *(uint4*)&VtV[0][vdv][vkg * 8] =
        *(const uint4*)&vsrc[(size_t)vdv * N_PTS + vkg * 8];
    if (u < 128)
      *(uint4*)&VtV[0][32 + vdv][vkg * 8] =
          *(const uint4*)&vsrc[(size_t)(32 + vdv) * N_PTS + vkg * 8];
  }
  __syncthreads();

  for (int kt = 0; kt < 16; ++kt) {
    int cur = kt & 1, nxt = cur ^ 1;
    uint4 kreg, vreg0, vreg1;
    if (kt < 15) {
      int key1 = (kt + 1) * 64;
      if (t < 256) {
        kreg = *(const uint4*)&ksrc[key1 * 32 + t * 8];
      } else {
        vreg0 = *(const uint4*)&vsrc[(size_t)vdv * N_PTS + key1 + vkg * 8];
        if (u < 128)
          vreg1 =
              *(const uint4*)&vsrc[(size_t)(32 + vdv) * N_PTS + key1 + vkg * 8];
      }
    }

    f32x4 sq[4];
    __builtin_amdgcn_s_setprio(1);
#pragma unroll
    for (int nt = 0; nt < 4; ++nt) {
      bf16x8 kf = *(const bf16x8*)&KsV[cur][nt * 16 + l15][g * 8];
      f32x4 z = (f32x4){0.f, 0.f, 0.f, 0.f};
      sq[nt] = __builtin_amdgcn_mfma_f32_16x16x32_bf16(kf, aq, z, 0, 0, 0);
    }
    __builtin_amdgcn_s_setprio(0);

    float tm = fmaxf(fmaxf(fmaxf(sq[0][0], sq[0][1]), fmaxf(sq[0][2], sq[0][3])),
                     fmaxf(fmaxf(sq[1][0], sq[1][1]), fmaxf(sq[1][2], sq[1][3])));
    tm = fmaxf(tm,
               fmaxf(fmaxf(fmaxf(sq[2][0], sq[2][1]), fmaxf(sq[2][2], sq[2][3])),
                     fmaxf(fmaxf(sq[3][0], sq[3][1]), fmaxf(sq[3][2], sq[3][3]))));
    tm = fmaxf(tm, __shfl_xor(tm, 16));
    tm = fmaxf(tm, __shfl_xor(tm, 32));
    float nm = fmaxf(mrun, tm);
    float corr = exp2f(mrun - nm);
    mrun = nm;
    float rs = 0.f;
#pragma unroll
    for (int nt = 0; nt < 4; ++nt)
#pragma unroll
      for (int r = 0; r < 4; ++r) {
        float p = exp2f(sq[nt][r] - nm);
        sq[nt][r] = p;
        rs += p;
      }
    rs += __shfl_xor(rs, 16);
    rs += __shfl_xor(rs, 32);
    lrun = lrun * corr + rs;
#pragma unroll
    for (int mt = 0; mt < 3; ++mt)
#pragma unroll
      for (int r = 0; r < 4; ++r) acco[mt][r] *= corr;

#pragma unroll
    for (int nt = 0; nt < 4; ++nt) {
      bf16x4 pk;
      pk[0] = (__bf16)sq[nt][0]; pk[1] = (__bf16)sq[nt][1];
      pk[2] = (__bf16)sq[nt][2]; pk[3] = (__bf16)sq[nt][3];
      *(bf16x4*)&Pbuf[w][l15][nt * 16 + g * 4] = pk;
    }
    bf16x8 ap[2];
#pragma unroll
    for (int kc = 0; kc < 2; ++kc)
      ap[kc] = *(const bf16x8*)&Pbuf[w][l15][kc * 32 + g * 8];

    __builtin_amdgcn_s_setprio(1);
#pragma unroll
    for (int mt = 0; mt < 3; ++mt)
#pragma unroll
      for (int kc = 0; kc < 2; ++kc) {
        bf16x8 vf = *(const bf16x8*)&VtV[cur][mt * 16 + l15][kc * 32 + g * 8];
        acco[mt] = __builtin_amdgcn_mfma_f32_16x16x32_bf16(vf, ap[kc],
                                                           acco[mt], 0, 0, 0);
      }
    __builtin_amdgcn_s_setprio(0);

    if (kt < 15) {
      if (t < 256) {
        *(uint4*)&KsV[nxt][t >> 2][(t & 3) * 8] = kreg;
      } else {
        *(uint4*)&VtV[nxt][vdv][vkg * 8] = vreg0;
        if (u < 128) *(uint4*)&VtV[nxt][32 + vdv][vkg * 8] = vreg1;
      }
      __syncthreads();
    }
  }

  float inv = 1.f / lrun;
  int row = b * N_PTS + nloc0 + l15;
#pragma unroll
  for (int mt = 0; mt < 2; ++mt) {
    ushort4 o;
    o.x = bfu(acco[mt][0] * inv); o.y = bfu(acco[mt][1] * inv);
    o.z = bfu(acco[mt][2] * inv); o.w = bfu(acco[mt][3] * inv);
    *(ushort4*)&av[(size_t)row * C_DIM + h * 32 + mt * 16 + g * 4] = o;
  }
  {
    const float* cp = &cor[(size_t)row * 3];
    float c0 = cp[0], c1 = cp[1], c2 = cp[2];
    ushort4 o;
#pragma unroll
    for (int r = 0; r < 4; ++r) {
      int md = h * 16 + g * 4 + r;
      float ce = c0 * cw[md * 3] + c1 * cw[md * 3 + 1] + c2 * cw[md * 3 + 2];
      float v = acco[2][r] * inv - ce;
      ((unsigned short*)&o)[r] = bfu(v);
    }
    *(ushort4*)&dmc[(size_t)row * MDIM_N + h * 16 + g * 4] = o;
  }
}

// ---------------------------------------------------------------- MFMA GEMM
// 2-barrier single-buffer. BM=128, 4 waves (2x2).
// MODE 1: fused q+kv (M=768): m0<256 -> qb*QSCALE head-major; 256..511 -> kb
//         head-major; >=512 -> vt transposed. A batch-swapped iff m0>=256.
// MODE 5: transposed float4 residual store (fc2)
template <int MODE, int BNt>
__global__ __launch_bounds__(256)
void mgemm_k(const __bf16* __restrict__ A, const __bf16* __restrict__ W,
             const float* __restrict__ bias, void* __restrict__ outp,
             const float* __restrict__ e0, __bf16* __restrict__ kbp,
             __bf16* __restrict__ vtp, int K, int M) {
  constexpr int WN = BNt / 2;
  constexpr int NR = WN / 16;
  __shared__ __bf16 Al[128 * 64];
  __shared__ __bf16 Bl[BNt * 64];
  int t = threadIdx.x;
  int w = t >> 6, lane = t & 63;
  int l15 = lane & 15, g = lane >> 4;
  int wr = w >> 1, wn = w & 1;
  int r0 = blockIdx.y * 128;
  int m0 = blockIdx.x * BNt;
  bool swapA = (MODE == 1) && (m0 >= 256);

  f32x4 acc[4][NR];
#pragma unroll
  for (int i = 0; i < 4; ++i)
#pragma unroll
    for (int j = 0; j < NR; ++j) acc[i][j] = (f32x4){0.f, 0.f, 0.f, 0.f};

  for (int kt = 0; kt < K; kt += 64) {
    __syncthreads();
#pragma unroll
    for (int p = 0; p < 4; ++p) {
      int flat = p * 256 + t;
      int row = flat >> 3, c16 = flat & 7;
      int gr = r0 + row;
      if (swapA) gr = ((((gr >> 10) + 4) & 7) << 10) | (gr & 1023);
      *(uint4*)&Al[row * 64 + (c16 ^ (row & 7)) * 8] =
          *(const uint4*)&A[(size_t)gr * K + kt + c16 * 8];
    }
#pragma unroll
    for (int p = 0; p < BNt / 32; ++p) {
      int flat = p * 256 + t;
      int row = flat >> 3, c16 = flat & 7;
      *(uint4*)&Bl[row * 64 + (c16 ^ (row & 7)) * 8] =
          *(const uint4*)&W[(size_t)(m0 + row) * K + kt + c16 * 8];
    }
    __syncthreads();
#pragma unroll
    for (int ks = 0; ks < 2; ++ks) {
      bf16x8 af[4], bf_[NR];
#pragma unroll
      for (int mf = 0; mf < 4; ++mf) {
        int row = wr * 64 + mf * 16 + l15;
        af[mf] = *(const bf16x8*)&Al[row * 64 + ((ks * 4 + g) ^ (l15 & 7)) * 8];
      }
#pragma unroll
      for (int nf = 0; nf < NR; ++nf) {
        int row = wn * WN + nf * 16 + l15;
        bf_[nf] = *(const bf16x8*)&Bl[row * 64 + ((ks * 4 + g) ^ (l15 & 7)) * 8];
      }
#pragma unroll
      for (int mf = 0; mf < 4; ++mf)
#pragma unroll
        for (int nf = 0; nf < NR; ++nf)
          acc[mf][nf] = __builtin_amdgcn_mfma_f32_16x16x32_bf16(
              af[mf], bf_[nf], acc[mf][nf], 0, 0, 0);
    }
  }

#pragma unroll
  for (int mf = 0; mf < 4; ++mf) {
#pragma unroll
    for (int nf = 0; nf < NR; ++nf) {
      int m = m0 + wn * WN + nf * 16 + l15;
      int rbase = r0 + wr * 64 + mf * 16 + g * 4;
      if (MODE == 5) {
        int b = rbase >> 10, n = rbase & 1023;
        size_t oi = (size_t)b * CN + (size_t)m * N_PTS + n;
        float4 xv = *(const float4*)&e0[oi];
        float bs = bias[m];
        float4 ov;
        ov.x = xv.x + acc[mf][nf][0] + bs;
        ov.y = xv.y + acc[mf][nf][1] + bs;
        ov.z = xv.z + acc[mf][nf][2] + bs;
        ov.w = xv.w + acc[mf][nf][3] + bs;
        *(float4*)&((float*)outp)[oi] = ov;
      } else if (MODE == 1 && m0 >= 512) {
        int d = m - 512, hh = d >> 5, dd = d & 31;
        int b = rbase >> 10, n0v = rbase & 1023;
        ushort4 uu;
        uu.x = bfu(acc[mf][nf][0]); uu.y = bfu(acc[mf][nf][1]);
        uu.z = bfu(acc[mf][nf][2]); uu.w = bfu(acc[mf][nf][3]);
        *(ushort4*)&vtp[(((size_t)b * 8 + hh) * 48 + dd) * 1024 + n0v] = uu;
      } else {
#pragma unroll
        for (int r = 0; r < 4; ++r) {
          float v = acc[mf][nf][r];
          int b = rbase >> 10, n = (rbase & 1023) + r;
          if (m0 < 256) {
            int hh = m >> 5, dd = m & 31;
            ((__bf16*)outp)[(((size_t)b * 8 + hh) * 1024 + n) * 32 + dd] =
                (__bf16)(v * QSCALE);
          } else {
            int d = m - 256, hh = d >> 5, dd = d & 31;
            kbp[(((size_t)b * 8 + hh) * 1024 + n) * 32 + dd] = (__bf16)v;
          }
        }
      }
    }
  }
}

// ------------------------------------- proj (+BN2 stats) and motion, fused
// blockIdx.x<4: xn2 = bf16(xnb) + av@proj_w^T + proj_b, stats->raw2.
// blockIdx.x>=4: motion = dmc@mproj_w^T + mproj_b.
__global__ __launch_bounds__(256)
void projmot_k(const __bf16* __restrict__ av, const __bf16* __restrict__ pw,
               const float* __restrict__ pb, float* __restrict__ xn2,
               const __bf16* __restrict__ xnb, const __bf16* __restrict__ dmc,
               const __bf16* __restrict__ mw, const float* __restrict__ mb,
               float* __restrict__ mot, float* __restrict__ raw2) {
  __shared__ __bf16 Al[128 * 64];
  __shared__ __bf16 Bl[64 * 64];
  bool isProj = blockIdx.x < 4;
  const __bf16* A = isProj ? av : dmc;
  const __bf16* W = isProj ? pw : mw;
  const float* bias = isProj ? pb : mb;
  int K = isProj ? 256 : 128;
  int m0 = (isProj ? blockIdx.x : (blockIdx.x - 4)) * 64;
  int t = threadIdx.x;
  int w = t >> 6, lane = t & 63;
  int l15 = lane & 15, g = lane >> 4;
  int wr = w >> 1, wn = w & 1;
  int r0 = blockIdx.y * 128;

  f32x4 acc[4][2];
#pragma unroll
  for (int i = 0; i < 4; ++i)
#pragma unroll
    for (int j = 0; j < 2; ++j) acc[i][j] = (f32x4){0.f, 0.f, 0.f, 0.f};

  for (int kt = 0; kt < K; kt += 64) {
    __syncthreads();
#pragma unroll
    for (int p = 0; p < 4; ++p) {
      int flat = p * 256 + t;
      int row = flat >> 3, c16 = flat & 7;
      *(uint4*)&Al[row * 64 + (c16 ^ (row & 7)) * 8] =
          *(const uint4*)&A[(size_t)(r0 + row) * K + kt + c16 * 8];
    }
#pragma unroll
    for (int p = 0; p < 2; ++p) {
      int flat = p * 256 + t;
      int row = flat >> 3, c16 = flat & 7;
      *(uint4*)&Bl[row * 64 + (c16 ^ (row & 7)) * 8] =
          *(const uint4*)&W[(size_t)(m0 + row) * K + kt + c16 * 8];
    }
    __syncthreads();
#pragma unroll
    for (int ks = 0; ks < 2; ++ks) {
      bf16x8 af[4], bf_[2];
#pragma unroll
      for (int mf = 0; mf < 4; ++mf) {
        int row = wr * 64 + mf * 16 + l15;
        af[mf] = *(const bf16x8*)&Al[row * 64 + ((ks * 4 + g) ^ (l15 & 7)) * 8];
      }
#pragma unroll
      for (int nf = 0; nf < 2; ++nf) {
        int row = wn * 32 + nf * 16 + l15;
        bf_[nf] = *(const bf16x8*)&Bl[row * 64 + ((ks * 4 + g) ^ (l15 & 7)) * 8];
      }
#pragma unroll
      for (int mf = 0; mf < 4; ++mf)
#pragma unroll
        for (int nf = 0; nf < 2; ++nf)
          acc[mf][nf] = __builtin_amdgcn_mfma_f32_16x16x32_bf16(
              af[mf], bf_[nf], acc[mf][nf], 0, 0, 0);
    }
  }

  float sS[2] = {0.f, 0.f}, sQ[2] = {0.f, 0.f};
#pragma unroll
  for (int mf = 0; mf < 4; ++mf) {
#pragma unroll
    for (int nf = 0; nf < 2; ++nf) {
      int m = m0 + wn * 32 + nf * 16 + l15;
      int rbase = r0 + wr * 64 + mf * 16 + g * 4;
#pragma unroll
      for (int r = 0; r < 4; ++r) {
        float v = acc[mf][nf][r];
        if (isProj) {
          size_t oi = (size_t)(rbase + r) * C_DIM + m;
          float vv = (float)xnb[oi] + v + bias[m];
          xn2[oi] = vv;
          sS[nf] += vv;
          sQ[nf] += vv * vv;
        } else {
          mot[(size_t)(rbase + r) * MDIM_N + m] = v + bias[m];
        }
      }
    }
  }

  if (isProj) {
    __syncthreads();
    float* colS = (float*)&Al[0];
    float* colQ = colS + 64;
    if (t < 128) colS[t] = 0.f;
    __syncthreads();
#pragma unroll
    for (int nf = 0; nf < 2; ++nf) {
      int mc = wn * 32 + nf * 16 + l15;
      atomicAdd(&colS[mc], sS[nf]);
      atomicAdd(&colQ[mc], sQ[nf]);
    }
    __syncthreads();
    if (t < 64) {
      atomicAdd(&raw2[m0 + t], colS[t]);
      atomicAdd(&raw2[256 + m0 + t], colQ[t]);
    }
  }
}

// ------------------------- fc1: BN2 finalize+apply fused into A-staging
// h = prelu(dw(bn2(xn2) @ fc1_w^T + fc1_b)), bf16 out. BM=128, BN=128.
__global__ __launch_bounds__(256)
void fc1_k(const float* __restrict__ xn2, const float* __restrict__ raw2,
           const float* __restrict__ g2, const float* __restrict__ b2,
           const __bf16* __restrict__ W, const float* __restrict__ bias,
           const float* __restrict__ dw_w, const float* __restrict__ dw_b,
           const float* __restrict__ pre, __bf16* __restrict__ hb) {
  __shared__ __bf16 Al[128 * 64];
  __shared__ __bf16 Bl[128 * 64];
  __shared__ float scs[256], shs[256];
  int t = threadIdx.x;
  int w = t >> 6, lane = t & 63;
  int l15 = lane & 15, g = lane >> 4;
  int wr = w >> 1, wn = w & 1;
  int r0 = blockIdx.y * 128;
  int m0 = blockIdx.x * 128;

  {
    float mean = raw2[t] * (1.f / 8192.f);
    float var  = raw2[256 + t] * (1.f / 8192.f) - mean * mean;
    float sc   = g2[t] * rsqrtf(var + EPSV);
    scs[t] = sc;
    shs[t] = b2[t] - mean * sc;
  }
  __syncthreads();

  f32x4 acc[4][4];
#pragma unroll
  for (int i = 0; i < 4; ++i)
#pragma unroll
    for (int j = 0; j < 4; ++j) acc[i][j] = (f32x4){0.f, 0.f, 0.f, 0.f};

  for (int kt = 0; kt < 256; kt += 64) {
    __syncthreads();
#pragma unroll
    for (int p = 0; p < 4; ++p) {
      int flat = p * 256 + t;
      int row = flat >> 3, c16 = flat & 7;
      int k = kt + c16 * 8;
      const float* src = &xn2[(size_t)(r0 + row) * C_DIM + k];
      float4 v0 = *(const float4*)src;
      float4 v1 = *(const float4*)(src + 4);
      float4 s0 = *(const float4*)&scs[k];
      float4 s1 = *(const float4*)&scs[k + 4];
      float4 h0 = *(const float4*)&shs[k];
      float4 h1 = *(const float4*)&shs[k + 4];
      bf16x8 a;
      a[0] = (__bf16)(v0.x * s0.x + h0.x);
      a[1] = (__bf16)(v0.y * s0.y + h0.y);
      a[2] = (__bf16)(v0.z * s0.z + h0.z);
      a[3] = (__bf16)(v0.w * s0.w + h0.w);
      a[4] = (__bf16)(v1.x * s1.x + h1.x);
      a[5] = (__bf16)(v1.y * s1.y + h1.y);
      a[6] = (__bf16)(v1.z * s1.z + h1.z);
      a[7] = (__bf16)(v1.w * s1.w + h1.w);
      *(bf16x8*)&Al[row * 64 + (c16 ^ (row & 7)) * 8] = a;
    }
#pragma unroll
    for (int p = 0; p < 4; ++p) {
      int flat = p * 256 + t;
      int row = flat >> 3, c16 = flat & 7;
      *(uint4*)&Bl[row * 64 + (c16 ^ (row & 7)) * 8] =
          *(const uint4*)&W[(size_t)(m0 + row) * 256 + kt + c16 * 8];
    }
    __syncthreads();
#pragma unroll
    for (int ks = 0; ks < 2; ++ks) {
      bf16x8 af[4], bf_[4];
#pragma unroll
      for (int mf = 0; mf < 4; ++mf) {
        int row = wr * 64 + mf * 16 + l15;
        af[mf] = *(const bf16x8*)&Al[row * 64 + ((ks * 4 + g) ^ (l15 & 7)) * 8];
      }
#pragma unroll
      for (int nf = 0; nf < 4; ++nf) {
        int row = wn * 64 + nf * 16 + l15;
        bf_[nf] = *(const bf16x8*)&Bl[row * 64 + ((ks * 4 + g) ^ (l15 & 7)) * 8];
      }
#pragma unroll
      for (int mf = 0; mf < 4; ++mf)
#pragma unroll
        for (int nf = 0; nf < 4; ++nf)
          acc[mf][nf] = __builtin_amdgcn_mfma_f32_16x16x32_bf16(
              af[mf], bf_[nf], acc[mf][nf], 0, 0, 0);
    }
  }

  float a_pre = pre[0];
#pragma unroll
  for (int mf = 0; mf < 4; ++mf) {
#pragma unroll
    for (int nf = 0; nf < 4; ++nf) {
      int m = m0 + wn * 64 + nf * 16 + l15;
      int rbase = r0 + wr * 64 + mf * 16 + g * 4;
      float bs = bias[m], dwm = dw_w[m], dbm = dw_b[m];
#pragma unroll
      for (int r = 0; r < 4; ++r) {
        float v = acc[mf][nf][r] + bs;
        v = v * dwm + dbm;
        hb[(size_t)(rbase + r) * HID_N + m] =
            (__bf16)(v >= 0.f ? v : a_pre * v);
      }
    }
  }
}

extern "C" void kernel_launch(void* const* d_in, const int* in_sizes, int n_in,
                              void* d_out, int out_size, void* d_ws,
                              size_t ws_size, hipStream_t stream) {
  const float* x       = (const float*)d_in[0];
  const float* cor     = (const float*)d_in[1];
  const float* q_w     = (const float*)d_in[2];
  const float* kv_w    = (const float*)d_in[3];
  const float* cor_w   = (const float*)d_in[4];
  const float* proj_w  = (const float*)d_in[5];
  const float* proj_b  = (const float*)d_in[6];
  const float* mproj_w = (const float*)d_in[7];
  const float* mproj_b = (const float*)d_in[8];
  const float* g1      = (const float*)d_in[9];
  const float* b1      = (const float*)d_in[10];
  const float* g2      = (const float*)d_in[11];
  const float* b2      = (const float*)d_in[12];
  const float* fc1_w   = (const float*)d_in[13];
  const float* fc1_b   = (const float*)d_in[14];
  const float* dw_w    = (const float*)d_in[15];
  const float* dw_b    = (const float*)d_in[16];
  const float* prelu   = (const float*)d_in[17];
  const float* fc2_w   = (const float*)d_in[18];
  const float* fc2_b   = (const float*)d_in[19];

  char* base = (char*)d_ws;
  const size_t MB = 1u << 20;
  __bf16* xnb  = (__bf16*)(base + 8 * MB);       // 8-12
  __bf16* qb   = (__bf16*)(base + 12 * MB);      // 12-16  [bh][n][32]
  __bf16* kb   = (__bf16*)(base + 16 * MB);      // 16-20  [bh][n][32]
  __bf16* vt   = (__bf16*)(base + 20 * MB);      // 20-26  [bh][48][1024]
  __bf16* av   = (__bf16*)(base + 30 * MB);      // 30-34
  __bf16* dmc  = (__bf16*)(base + 34 * MB);      // 34-36
  float*  xn2  = (float*)(base + 36 * MB);       // 36-44 f32
  __bf16* hb   = (__bf16*)(base + 12 * MB);      // overlay 12-28 (fc1 out)
  __bf16* qwb  = (__bf16*)(base + 44 * MB);            // 128 KB (q_w)
  __bf16* kvwb = (__bf16*)(base + 44 * MB + 131072);   // 256 KB (kv_w, adj)
  __bf16* pwb  = (__bf16*)(base + 44 * MB + 393216);
  __bf16* mwb  = (__bf16*)(base + 44 * MB + 524288);
  __bf16* f1wb = (__bf16*)(base + 44 * MB + 557056);
  __bf16* f2wb = (__bf16*)(base + 44 * MB + 1081344);
  float*  raw2 = (float*)(base + 45 * MB + 655360);
  float*  st1  = raw2 + 1024;
  float* out0 = (float*)d_out;
  float* out1 = out0 + 2097152;

  (void)hipMemsetAsync(raw2, 0, 512 * sizeof(float), stream);

  // prep: weight cvt + ceh->vt + BN1 stats (one launch)
  prep_k<<<1296, 256, 0, stream>>>(q_w, kv_w, proj_w, mproj_w, fc1_w, fc2_w,
                                   qwb, kvwb, pwb, mwb, f1wb, f2wb,
                                   cor, cor_w, vt, x, g1, b1, st1);
  norm1_t_k<<<dim3(8, 32, 8), dim3(32, 8), 0, stream>>>(x, st1, xnb);

  // fused q+kv GEMM: W = [q_w; kv_w] (adjacent in ws), M=768
  mgemm_k<1, 128><<<dim3(6, 64), 256, 0, stream>>>(
      xnb, qwb, nullptr, qb, nullptr, kb, vt, 256, 768);

  attn_k<<<dim3(64, 8), 512, 0, stream>>>(qb, kb, vt, cor, cor_w, av, dmc);

  // proj(+BN2 stats) and motion in one launch
  projmot_k<<<dim3(6, 64), 256, 0, stream>>>(av, pwb, proj_b, xn2, xnb,
                                             dmc, mwb, mproj_b, out1, raw2);

  // fc1 with fused BN2 finalize+apply
  fc1_k<<<dim3(8, 64), 256, 0, stream>>>(xn2, raw2, g2, b2, f1wb, fc1_b,
                                         dw_w, dw_b, prelu, hb);

  // x_out = x + (h @ fc2_w^T + fc2_b)^T (f32, transposed float4 store)
  mgemm_k<5, 64><<<dim3(4, 64), 256, 0, stream>>>(
      hb, f2wb, fc2_b, out0, x, nullptr, nullptr, HID_N, 256);
}

// Round 12
// 111.913 us; speedup vs baseline: 1.1035x; 1.1035x over previous
//
#include <hip/hip_runtime.h>
#include <hip/hip_bf16.h>
#include <math.h>

// MotionFormerBlock: bf16 MFMA GEMMs + swapped-operand MFMA flash attn
// (K-from-global, 128-key steps, defer-max). 8 dispatches.
#define C_DIM 256
#define N_PTS 1024
#define H_N 8
#define MDIM_N 128
#define HID_N 1024
#define EPSV 1e-5f
#define R_TOT 8192
#define CN 262144               // C_DIM * N_PTS

typedef __bf16 bf16x8 __attribute__((ext_vector_type(8)));
typedef __bf16 bf16x4 __attribute__((ext_vector_type(4)));
typedef float f32x4 __attribute__((ext_vector_type(4)));

// softmax scale * log2(e): 32^-0.5 * 1.4426950408889634
#define QSCALE 0.25503482f

__device__ inline unsigned short bfu(float f) {
  union { __bf16 h; unsigned short u; } c;
  c.h = (__bf16)f;
  return c.u;
}

// ---------------------------------------------------- prep: wcvt + cet + bn1
__global__ __launch_bounds__(256)
void prep_k(const float* __restrict__ s0, const float* __restrict__ s1,
            const float* __restrict__ s2, const float* __restrict__ s3,
            const float* __restrict__ s4, const float* __restrict__ s5,
            __bf16* d0, __bf16* d1, __bf16* d2, __bf16* d3, __bf16* d4,
            __bf16* d5, const float* __restrict__ cor,
            const float* __restrict__ cw, __bf16* __restrict__ vt,
            const float* __restrict__ x, const float* __restrict__ g1,
            const float* __restrict__ b1, float* __restrict__ st) {
  int blk = blockIdx.x;
  int t = threadIdx.x;
  if (blk < 784) {
    int i = blk * 256 + t;
    const float* s; __bf16* d; int off;
    if      (i <  16384) { s = s0; d = d0; off = 0; }
    else if (i <  49152) { s = s1; d = d1; off = 16384; }
    else if (i <  65536) { s = s2; d = d2; off = 49152; }
    else if (i <  69632) { s = s3; d = d3; off = 65536; }
    else if (i < 135168) { s = s4; d = d4; off = 69632; }
    else                 { s = s5; d = d5; off = 135168; }
    int j = i - off;
    float4 v = ((const float4*)s)[j];
    ushort4 u;
    u.x = bfu(v.x); u.y = bfu(v.y); u.z = bfu(v.z); u.w = bfu(v.w);
    ((ushort4*)d)[j] = u;
  } else if (blk < 1040) {
    __shared__ float cs[768];
    int j = blk - 784;
    int bh = j & 63, b = bh >> 3, h = bh & 7;
    int n0 = (j >> 6) * 256;
    for (int i = t; i < 768; i += 256)
      cs[i] = cor[(size_t)(b * N_PTS + n0) * 3 + i];
    __syncthreads();
    int md = t >> 4, ns = (t & 15) * 16;
    float w0 = cw[(h * 16 + md) * 3 + 0];
    float w1 = cw[(h * 16 + md) * 3 + 1];
    float w2 = cw[(h * 16 + md) * 3 + 2];
    __bf16* dst = &vt[((size_t)bh * 48 + 32 + md) * 1024 + n0 + ns];
#pragma unroll
    for (int g2 = 0; g2 < 4; ++g2) {
      ushort4 u;
      float v0 = cs[(ns + g2 * 4 + 0) * 3] * w0 + cs[(ns + g2 * 4 + 0) * 3 + 1] * w1 + cs[(ns + g2 * 4 + 0) * 3 + 2] * w2;
      float v1 = cs[(ns + g2 * 4 + 1) * 3] * w0 + cs[(ns + g2 * 4 + 1) * 3 + 1] * w1 + cs[(ns + g2 * 4 + 1) * 3 + 2] * w2;
      float v2 = cs[(ns + g2 * 4 + 2) * 3] * w0 + cs[(ns + g2 * 4 + 2) * 3 + 1] * w1 + cs[(ns + g2 * 4 + 2) * 3 + 2] * w2;
      float v3 = cs[(ns + g2 * 4 + 3) * 3] * w0 + cs[(ns + g2 * 4 + 3) * 3 + 1] * w1 + cs[(ns + g2 * 4 + 3) * 3 + 2] * w2;
      u.x = bfu(v0); u.y = bfu(v1); u.z = bfu(v2); u.w = bfu(v3);
      *(ushort4*)&dst[g2 * 4] = u;
    }
  } else {
    __shared__ float ss[256], sq[256];
    int c = blk - 1040;
    float s = 0.f, q = 0.f;
    for (int i = 0; i < 32; ++i) {
      int idx = t + i * 256;
      int b = idx >> 10, n = idx & 1023;
      float v = x[(size_t)b * CN + (size_t)c * N_PTS + n];
      s += v; q += v * v;
    }
    ss[t] = s; sq[t] = q;
    __syncthreads();
    for (int off = 128; off > 0; off >>= 1) {
      if (t < off) { ss[t] += ss[t + off]; sq[t] += sq[t + off]; }
      __syncthreads();
    }
    if (t == 0) {
      float mean = ss[0] * (1.f / 8192.f);
      float var  = sq[0] * (1.f / 8192.f) - mean * mean;
      float sc   = g1[c] * rsqrtf(var + EPSV);
      st[c]          = sc;
      st[C_DIM + c]  = b1[c] - mean * sc;
    }
  }
}

// ------------------------------------------- normalize + transpose (bf16)
__global__ __launch_bounds__(256)
void norm1_t_k(const float* __restrict__ x, const float* __restrict__ st,
               __bf16* __restrict__ xnb) {
  __shared__ float tile[32][33];
  int c0 = blockIdx.x * 32, n0 = blockIdx.y * 32, b = blockIdx.z;
  int tx = threadIdx.x, ty = threadIdx.y;
#pragma unroll
  for (int k = 0; k < 4; ++k) {
    int ci = ty + k * 8;
    int c = c0 + ci;
    float v = x[(size_t)b * CN + (size_t)c * N_PTS + n0 + tx];
    tile[ci][tx] = v * st[c] + st[C_DIM + c];
  }
  __syncthreads();
#pragma unroll
  for (int k = 0; k < 4; ++k) {
    int ni = ty + k * 8;
    xnb[((size_t)(b * N_PTS + n0 + ni)) * C_DIM + c0 + tx] =
        (__bf16)tile[tx][ni];
  }
}

// ---------------------------------------------------------------- MFMA attention
// 8 waves x 16 q-rows (512 thr). K fragments read DIRECTLY from global kb
// (coalesced 1KB/fragment, L2-resident). V' LDS double-buffered, 128-key
// steps (8 barriers total). Softmax in-register, defer-max (THR=3, exp2).
__global__ __launch_bounds__(512)
void attn_k(const __bf16* __restrict__ qb, const __bf16* __restrict__ kb,
            const __bf16* __restrict__ vt, const float* __restrict__ cor,
            const float* __restrict__ cw, __bf16* __restrict__ av,
            __bf16* __restrict__ dmc) {
  __shared__ __bf16 Vt[2][48][136];   // 26.1 KB
  __shared__ __bf16 Pbuf[8][16][72];  // 18.4 KB

  int bh = blockIdx.x; int b = bh >> 3, h = bh & 7;
  int t = threadIdx.x;
  int w = t >> 6, lane = t & 63;
  int l15 = lane & 15, g = lane >> 4;

  int nloc0 = blockIdx.y * 128 + w * 16;
  bf16x8 aq =
      *(const bf16x8*)&qb[((size_t)bh * N_PTS + nloc0 + l15) * 32 + g * 8];

  const __bf16* ksrc = kb + (size_t)bh * N_PTS * 32;
  const __bf16* vsrc = vt + (size_t)bh * 48 * N_PTS;
  int vdv = t >> 4, vkg = t & 15;     // V slot t -> rows 0..31; slot 512+t -> 32..47

  float mrun = -1e30f, lrun = 0.f;
  f32x4 acco[3];
#pragma unroll
  for (int mt = 0; mt < 3; ++mt) acco[mt] = (f32x4){0.f, 0.f, 0.f, 0.f};

  // prologue: stage V keys 0..127 into buf 0
  *(uint4*)&Vt[0][vdv][vkg * 8] =
      *(const uint4*)&vsrc[(size_t)vdv * N_PTS + vkg * 8];
  if (t < 256)
    *(uint4*)&Vt[0][32 + vdv][vkg * 8] =
        *(const uint4*)&vsrc[(size_t)(32 + vdv) * N_PTS + vkg * 8];
  __syncthreads();

  for (int kt = 0; kt < 8; ++kt) {
    int cur = kt & 1, nxt = cur ^ 1;
    uint4 vregA, vregB;
    if (kt < 7) {
      int key1 = (kt + 1) * 128;
      vregA = *(const uint4*)&vsrc[(size_t)vdv * N_PTS + key1 + vkg * 8];
      if (t < 256)
        vregB =
            *(const uint4*)&vsrc[(size_t)(32 + vdv) * N_PTS + key1 + vkg * 8];
    }

    // ---- S^T = K Q^T over 128 keys, K fragments from global (coalesced)
    f32x4 sq[8];
    const __bf16* kbase = &ksrc[(size_t)(kt * 128 + l15) * 32 + g * 8];
    __builtin_amdgcn_s_setprio(1);
#pragma unroll
    for (int nt = 0; nt < 8; ++nt) {
      bf16x8 kf = *(const bf16x8*)(kbase + nt * 512);
      f32x4 z = (f32x4){0.f, 0.f, 0.f, 0.f};
      sq[nt] = __builtin_amdgcn_mfma_f32_16x16x32_bf16(kf, aq, z, 0, 0, 0);
    }
    __builtin_amdgcn_s_setprio(0);

    // ---- softmax over 32 per-lane values (row q=l15), defer-max THR=3
    float m0 = fmaxf(fmaxf(sq[0][0], sq[0][1]), fmaxf(sq[0][2], sq[0][3]));
    float m1 = fmaxf(fmaxf(sq[1][0], sq[1][1]), fmaxf(sq[1][2], sq[1][3]));
    float m2 = fmaxf(fmaxf(sq[2][0], sq[2][1]), fmaxf(sq[2][2], sq[2][3]));
    float m3 = fmaxf(fmaxf(sq[3][0], sq[3][1]), fmaxf(sq[3][2], sq[3][3]));
    float m4 = fmaxf(fmaxf(sq[4][0], sq[4][1]), fmaxf(sq[4][2], sq[4][3]));
    float m5 = fmaxf(fmaxf(sq[5][0], sq[5][1]), fmaxf(sq[5][2], sq[5][3]));
    float m6 = fmaxf(fmaxf(sq[6][0], sq[6][1]), fmaxf(sq[6][2], sq[6][3]));
    float m7 = fmaxf(fmaxf(sq[7][0], sq[7][1]), fmaxf(sq[7][2], sq[7][3]));
    float tm = fmaxf(fmaxf(fmaxf(m0, m1), fmaxf(m2, m3)),
                     fmaxf(fmaxf(m4, m5), fmaxf(m6, m7)));
    tm = fmaxf(tm, __shfl_xor(tm, 16));
    tm = fmaxf(tm, __shfl_xor(tm, 32));
    if (__ballot(tm > mrun + 3.0f) != 0ull) {
      float nm = fmaxf(mrun, tm);
      float corr = exp2f(mrun - nm);
      mrun = nm;
      lrun *= corr;
#pragma unroll
      for (int mt = 0; mt < 3; ++mt)
#pragma unroll
        for (int r = 0; r < 4; ++r) acco[mt][r] *= corr;
    }
#pragma unroll
    for (int nt = 0; nt < 8; ++nt)
#pragma unroll
      for (int r = 0; r < 4; ++r) sq[nt][r] = exp2f(sq[nt][r] - mrun);
    float s0 = (sq[0][0] + sq[0][1]) + (sq[0][2] + sq[0][3]);
    float s1 = (sq[1][0] + sq[1][1]) + (sq[1][2] + sq[1][3]);
    float s2 = (sq[2][0] + sq[2][1]) + (sq[2][2] + sq[2][3]);
    float s3 = (sq[3][0] + sq[3][1]) + (sq[3][2] + sq[3][3]);
    float s4 = (sq[4][0] + sq[4][1]) + (sq[4][2] + sq[4][3]);
    float s5 = (sq[5][0] + sq[5][1]) + (sq[5][2] + sq[5][3]);
    float s6 = (sq[6][0] + sq[6][1]) + (sq[6][2] + sq[6][3]);
    float s7 = (sq[7][0] + sq[7][1]) + (sq[7][2] + sq[7][3]);
    float rs = ((s0 + s1) + (s2 + s3)) + ((s4 + s5) + (s6 + s7));
    rs += __shfl_xor(rs, 16);
    rs += __shfl_xor(rs, 32);
    lrun += rs;

    // ---- PV in two 64-key halves (Pbuf reused wave-internally)
#pragma unroll
    for (int half = 0; half < 2; ++half) {
#pragma unroll
      for (int nt2 = 0; nt2 < 4; ++nt2) {
        int nt = half * 4 + nt2;
        bf16x4 pk;
        pk[0] = (__bf16)sq[nt][0]; pk[1] = (__bf16)sq[nt][1];
        pk[2] = (__bf16)sq[nt][2]; pk[3] = (__bf16)sq[nt][3];
        *(bf16x4*)&Pbuf[w][l15][nt2 * 16 + g * 4] = pk;
      }
      bf16x8 ap0 = *(const bf16x8*)&Pbuf[w][l15][g * 8];
      bf16x8 ap1 = *(const bf16x8*)&Pbuf[w][l15][32 + g * 8];
      __builtin_amdgcn_s_setprio(1);
#pragma unroll
      for (int mt = 0; mt < 3; ++mt) {
        bf16x8 vf0 =
            *(const bf16x8*)&Vt[cur][mt * 16 + l15][half * 64 + g * 8];
        acco[mt] =
            __builtin_amdgcn_mfma_f32_16x16x32_bf16(vf0, ap0, acco[mt], 0, 0, 0);
        bf16x8 vf1 =
            *(const bf16x8*)&Vt[cur][mt * 16 + l15][half * 64 + 32 + g * 8];
        acco[mt] =
            __builtin_amdgcn_mfma_f32_16x16x32_bf16(vf1, ap1, acco[mt], 0, 0, 0);
      }
      __builtin_amdgcn_s_setprio(0);
    }

    // ---- write staged V into the other buffer; one barrier per step
    if (kt < 7) {
      *(uint4*)&Vt[nxt][vdv][vkg * 8] = vregA;
      if (t < 256) *(uint4*)&Vt[nxt][32 + vdv][vkg * 8] = vregB;
      __syncthreads();
    }
  }

  float inv = 1.f / lrun;
  int row = b * N_PTS + nloc0 + l15;
#pragma unroll
  for (int mt = 0; mt < 2; ++mt) {
    ushort4 o;
    o.x = bfu(acco[mt][0] * inv); o.y = bfu(acco[mt][1] * inv);
    o.z = bfu(acco[mt][2] * inv); o.w = bfu(acco[mt][3] * inv);
    *(ushort4*)&av[(size_t)row * C_DIM + h * 32 + mt * 16 + g * 4] = o;
  }
  {
    const float* cp = &cor[(size_t)row * 3];
    float c0 = cp[0], c1 = cp[1], c2 = cp[2];
    ushort4 o;
#pragma unroll
    for (int r = 0; r < 4; ++r) {
      int md = h * 16 + g * 4 + r;
      float ce = c0 * cw[md * 3] + c1 * cw[md * 3 + 1] + c2 * cw[md * 3 + 2];
      float v = acco[2][r] * inv - ce;
      ((unsigned short*)&o)[r] = bfu(v);
    }
    *(ushort4*)&dmc[(size_t)row * MDIM_N + h * 16 + g * 4] = o;
  }
}

// ---------------------------------------------------------------- MFMA GEMM
// 2-barrier single-buffer. BM=128, 4 waves (2x2).
// MODE 1: fused q+kv (M=768). MODE 5: fc2 transposed residual store.
template <int MODE, int BNt>
__global__ __launch_bounds__(256)
void mgemm_k(const __bf16* __restrict__ A, const __bf16* __restrict__ W,
             const float* __restrict__ bias, void* __restrict__ outp,
             const float* __restrict__ e0, __bf16* __restrict__ kbp,
             __bf16* __restrict__ vtp, int K, int M) {
  constexpr int WN = BNt / 2;
  constexpr int NR = WN / 16;
  __shared__ __bf16 Al[128 * 64];
  __shared__ __bf16 Bl[BNt * 64];
  int t = threadIdx.x;
  int w = t >> 6, lane = t & 63;
  int l15 = lane & 15, g = lane >> 4;
  int wr = w >> 1, wn = w & 1;
  int r0 = blockIdx.y * 128;
  int m0 = blockIdx.x * BNt;
  bool swapA = (MODE == 1) && (m0 >= 256);

  f32x4 acc[4][NR];
#pragma unroll
  for (int i = 0; i < 4; ++i)
#pragma unroll
    for (int j = 0; j < NR; ++j) acc[i][j] = (f32x4){0.f, 0.f, 0.f, 0.f};

  for (int kt = 0; kt < K; kt += 64) {
    __syncthreads();
#pragma unroll
    for (int p = 0; p < 4; ++p) {
      int flat = p * 256 + t;
      int row = flat >> 3, c16 = flat & 7;
      int gr = r0 + row;
      if (swapA) gr = ((((gr >> 10) + 4) & 7) << 10) | (gr & 1023);
      *(uint4*)&Al[row * 64 + (c16 ^ (row & 7)) * 8] =
          *(const uint4*)&A[(size_t)gr * K + kt + c16 * 8];
    }
#pragma unroll
    for (int p = 0; p < BNt / 32; ++p) {
      int flat = p * 256 + t;
      int row = flat >> 3, c16 = flat & 7;
      *(uint4*)&Bl[row * 64 + (c16 ^ (row & 7)) * 8] =
          *(const uint4*)&W[(size_t)(m0 + row) * K + kt + c16 * 8];
    }
    __syncthreads();
#pragma unroll
    for (int ks = 0; ks < 2; ++ks) {
      bf16x8 af[4], bf_[NR];
#pragma unroll
      for (int mf = 0; mf < 4; ++mf) {
        int row = wr * 64 + mf * 16 + l15;
        af[mf] = *(const bf16x8*)&Al[row * 64 + ((ks * 4 + g) ^ (l15 & 7)) * 8];
      }
#pragma unroll
      for (int nf = 0; nf < NR; ++nf) {
        int row = wn * WN + nf * 16 + l15;
        bf_[nf] = *(const bf16x8*)&Bl[row * 64 + ((ks * 4 + g) ^ (l15 & 7)) * 8];
      }
#pragma unroll
      for (int mf = 0; mf < 4; ++mf)
#pragma unroll
        for (int nf = 0; nf < NR; ++nf)
          acc[mf][nf] = __builtin_amdgcn_mfma_f32_16x16x32_bf16(
              af[mf], bf_[nf], acc[mf][nf], 0, 0, 0);
    }
  }

#pragma unroll
  for (int mf = 0; mf < 4; ++mf) {
#pragma unroll
    for (int nf = 0; nf < NR; ++nf) {
      int m = m0 + wn * WN + nf * 16 + l15;
      int rbase = r0 + wr * 64 + mf * 16 + g * 4;
      if (MODE == 5) {
        int b = rbase >> 10, n = rbase & 1023;
        size_t oi = (size_t)b * CN + (size_t)m * N_PTS + n;
        float4 xv = *(const float4*)&e0[oi];
        float bs = bias[m];
        float4 ov;
        ov.x = xv.x + acc[mf][nf][0] + bs;
        ov.y = xv.y + acc[mf][nf][1] + bs;
        ov.z = xv.z + acc[mf][nf][2] + bs;
        ov.w = xv.w + acc[mf][nf][3] + bs;
        *(float4*)&((float*)outp)[oi] = ov;
      } else if (MODE == 1 && m0 >= 512) {
        int d = m - 512, hh = d >> 5, dd = d & 31;
        int b = rbase >> 10, n0v = rbase & 1023;
        ushort4 uu;
        uu.x = bfu(acc[mf][nf][0]); uu.y = bfu(acc[mf][nf][1]);
        uu.z = bfu(acc[mf][nf][2]); uu.w = bfu(acc[mf][nf][3]);
        *(ushort4*)&vtp[(((size_t)b * 8 + hh) * 48 + dd) * 1024 + n0v] = uu;
      } else {
#pragma unroll
        for (int r = 0; r < 4; ++r) {
          float v = acc[mf][nf][r];
          int b = rbase >> 10, n = (rbase & 1023) + r;
          if (m0 < 256) {
            int hh = m >> 5, dd = m & 31;
            ((__bf16*)outp)[(((size_t)b * 8 + hh) * 1024 + n) * 32 + dd] =
                (__bf16)(v * QSCALE);
          } else {
            int d = m - 256, hh = d >> 5, dd = d & 31;
            kbp[(((size_t)b * 8 + hh) * 1024 + n) * 32 + dd] = (__bf16)v;
          }
        }
      }
    }
  }
}

// ------------------------------------- proj (+BN2 stats) and motion, fused
// blockIdx.x<4: xn2b = bf16(bf16(xnb) + av@proj_w^T + proj_b), stats->raw2.
// blockIdx.x>=4: motion = dmc@mproj_w^T + mproj_b.
__global__ __launch_bounds__(256)
void projmot_k(const __bf16* __restrict__ av, const __bf16* __restrict__ pw,
               const float* __restrict__ pb, __bf16* __restrict__ xn2b,
               const __bf16* __restrict__ xnb, const __bf16* __restrict__ dmc,
               const __bf16* __restrict__ mw, const float* __restrict__ mb,
               float* __restrict__ mot, float* __restrict__ raw2) {
  __shared__ __bf16 Al[128 * 64];
  __shared__ __bf16 Bl[64 * 64];
  bool isProj = blockIdx.x < 4;
  const __bf16* A = isProj ? av : dmc;
  const __bf16* W = isProj ? pw : mw;
  const float* bias = isProj ? pb : mb;
  int K = isProj ? 256 : 128;
  int m0 = (isProj ? blockIdx.x : (blockIdx.x - 4)) * 64;
  int t = threadIdx.x;
  int w = t >> 6, lane = t & 63;
  int l15 = lane & 15, g = lane >> 4;
  int wr = w >> 1, wn = w & 1;
  int r0 = blockIdx.y * 128;

  f32x4 acc[4][2];
#pragma unroll
  for (int i = 0; i < 4; ++i)
#pragma unroll
    for (int j = 0; j < 2; ++j) acc[i][j] = (f32x4){0.f, 0.f, 0.f, 0.f};

  for (int kt = 0; kt < K; kt += 64) {
    __syncthreads();
#pragma unroll
    for (int p = 0; p < 4; ++p) {
      int flat = p * 256 + t;
      int row = flat >> 3, c16 = flat & 7;
      *(uint4*)&Al[row * 64 + (c16 ^ (row & 7)) * 8] =
          *(const uint4*)&A[(size_t)(r0 + row) * K + kt + c16 * 8];
    }
#pragma unroll
    for (int p = 0; p < 2; ++p) {
      int flat = p * 256 + t;
      int row = flat >> 3, c16 = flat & 7;
      *(uint4*)&Bl[row * 64 + (c16 ^ (row & 7)) * 8] =
          *(const uint4*)&W[(size_t)(m0 + row) * K + kt + c16 * 8];
    }
    __syncthreads();
#pragma unroll
    for (int ks = 0; ks < 2; ++ks) {
      bf16x8 af[4], bf_[2];
#pragma unroll
      for (int mf = 0; mf < 4; ++mf) {
        int row = wr * 64 + mf * 16 + l15;
        af[mf] = *(const bf16x8*)&Al[row * 64 + ((ks * 4 + g) ^ (l15 & 7)) * 8];
      }
#pragma unroll
      for (int nf = 0; nf < 2; ++nf) {
        int row = wn * 32 + nf * 16 + l15;
        bf_[nf] = *(const bf16x8*)&Bl[row * 64 + ((ks * 4 + g) ^ (l15 & 7)) * 8];
      }
#pragma unroll
      for (int mf = 0; mf < 4; ++mf)
#pragma unroll
        for (int nf = 0; nf < 2; ++nf)
          acc[mf][nf] = __builtin_amdgcn_mfma_f32_16x16x32_bf16(
              af[mf], bf_[nf], acc[mf][nf], 0, 0, 0);
    }
  }

  float sS[2] = {0.f, 0.f}, sQ[2] = {0.f, 0.f};
#pragma unroll
  for (int mf = 0; mf < 4; ++mf) {
#pragma unroll
    for (int nf = 0; nf < 2; ++nf) {
      int m = m0 + wn * 32 + nf * 16 + l15;
      int rbase = r0 + wr * 64 + mf * 16 + g * 4;
#pragma unroll
      for (int r = 0; r < 4; ++r) {
        float v = acc[mf][nf][r];
        if (isProj) {
          size_t oi = (size_t)(rbase + r) * C_DIM + m;
          float vv = (float)xnb[oi] + v + bias[m];
          xn2b[oi] = (__bf16)vv;
          sS[nf] += vv;
          sQ[nf] += vv * vv;
        } else {
          mot[(size_t)(rbase + r) * MDIM_N + m] = v + bias[m];
        }
      }
    }
  }

  if (isProj) {
    __syncthreads();
    float* colS = (float*)&Al[0];
    float* colQ = colS + 64;
    if (t < 128) colS[t] = 0.f;
    __syncthreads();
#pragma unroll
    for (int nf = 0; nf < 2; ++nf) {
      int mc = wn * 32 + nf * 16 + l15;
      atomicAdd(&colS[mc], sS[nf]);
      atomicAdd(&colQ[mc], sQ[nf]);
    }
    __syncthreads();
    if (t < 64) {
      atomicAdd(&raw2[m0 + t], colS[t]);
      atomicAdd(&raw2[256 + m0 + t], colQ[t]);
    }
  }
}

// ------------------------- fc1: BN2 finalize+apply fused into bf16 A-staging
__global__ __launch_bounds__(256)
void fc1_k(const __bf16* __restrict__ xn2b, const float* __restrict__ raw2,
           const float* __restrict__ g2, const float* __restrict__ b2,
           const __bf16* __restrict__ W, const float* __restrict__ bias,
           const float* __restrict__ dw_w, const float* __restrict__ dw_b,
           const float* __restrict__ pre, __bf16* __restrict__ hb) {
  __shared__ __bf16 Al[128 * 64];
  __shared__ __bf16 Bl[128 * 64];
  __shared__ float scs[256], shs[256];
  int t = threadIdx.x;
  int w = t >> 6, lane = t & 63;
  int l15 = lane & 15, g = lane >> 4;
  int wr = w >> 1, wn = w & 1;
  int r0 = blockIdx.y * 128;
  int m0 = blockIdx.x * 128;

  {
    float mean = raw2[t] * (1.f / 8192.f);
    float var  = raw2[256 + t] * (1.f / 8192.f) - mean * mean;
    float sc   = g2[t] * rsqrtf(var + EPSV);
    scs[t] = sc;
    shs[t] = b2[t] - mean * sc;
  }
  __syncthreads();

  f32x4 acc[4][4];
#pragma unroll
  for (int i = 0; i < 4; ++i)
#pragma unroll
    for (int j = 0; j < 4; ++j) acc[i][j] = (f32x4){0.f, 0.f, 0.f, 0.f};

  for (int kt = 0; kt < 256; kt += 64) {
    __syncthreads();
#pragma unroll
    for (int p = 0; p < 4; ++p) {
      int flat = p * 256 + t;
      int row = flat >> 3, c16 = flat & 7;
      int k = kt + c16 * 8;
      bf16x8 v8 = *(const bf16x8*)&xn2b[(size_t)(r0 + row) * C_DIM + k];
      bf16x8 a;
#pragma unroll
      for (int i = 0; i < 8; ++i)
        a[i] = (__bf16)((float)v8[i] * scs[k + i] + shs[k + i]);
      *(bf16x8*)&Al[row * 64 + (c16 ^ (row & 7)) * 8] = a;
    }
#pragma unroll
    for (int p = 0; p < 4; ++p) {
      int flat = p * 256 + t;
      int row = flat >> 3, c16 = flat & 7;
      *(uint4*)&Bl[row * 64 + (c16 ^ (row & 7)) * 8] =
          *(const uint4*)&W[(size_t)(m0 + row) * 256 + kt + c16 * 8];
    }
    __syncthreads();
#pragma unroll
    for (int ks = 0; ks < 2; ++ks) {
      bf16x8 af[4], bf_[4];
#pragma unroll
      for (int mf = 0; mf < 4; ++mf) {
        int row = wr * 64 + mf * 16 + l15;
        af[mf] = *(const bf16x8*)&Al[row * 64 + ((ks * 4 + g) ^ (l15 & 7)) * 8];
      }
#pragma unroll
      for (int nf = 0; nf < 4; ++nf) {
        int row = wn * 64 + nf * 16 + l15;
        bf_[nf] = *(const bf16x8*)&Bl[row * 64 + ((ks * 4 + g) ^ (l15 & 7)) * 8];
      }
#pragma unroll
      for (int mf = 0; mf < 4; ++mf)
#pragma unroll
        for (int nf = 0; nf < 4; ++nf)
          acc[mf][nf] = __builtin_amdgcn_mfma_f32_16x16x32_bf16(
              af[mf], bf_[nf], acc[mf][nf], 0, 0, 0);
    }
  }

  float a_pre = pre[0];
#pragma unroll
  for (int mf = 0; mf < 4; ++mf) {
#pragma unroll
    for (int nf = 0; nf < 4; ++nf) {
      int m = m0 + wn * 64 + nf * 16 + l15;
      int rbase = r0 + wr * 64 + mf * 16 + g * 4;
      float bs = bias[m], dwm = dw_w[m], dbm = dw_b[m];
#pragma unroll
      for (int r = 0; r < 4; ++r) {
        float v = acc[mf][nf][r] + bs;
        v = v * dwm + dbm;
        hb[(size_t)(rbase + r) * HID_N + m] =
            (__bf16)(v >= 0.f ? v : a_pre * v);
      }
    }
  }
}

extern "C" void kernel_launch(void* const* d_in, const int* in_sizes, int n_in,
                              void* d_out, int out_size, void* d_ws,
                              size_t ws_size, hipStream_t stream) {
  const float* x       = (const float*)d_in[0];
  const float* cor     = (const float*)d_in[1];
  const float* q_w     = (const float*)d_in[2];
  const float* kv_w    = (const float*)d_in[3];
  const float* cor_w   = (const float*)d_in[4];
  const float* proj_w  = (const float*)d_in[5];
  const float* proj_b  = (const float*)d_in[6];
  const float* mproj_w = (const float*)d_in[7];
  const float* mproj_b = (const float*)d_in[8];
  const float* g1      = (const float*)d_in[9];
  const float* b1      = (const float*)d_in[10];
  const float* g2      = (const float*)d_in[11];
  const float* b2      = (const float*)d_in[12];
  const float* fc1_w   = (const float*)d_in[13];
  const float* fc1_b   = (const float*)d_in[14];
  const float* dw_w    = (const float*)d_in[15];
  const float* dw_b    = (const float*)d_in[16];
  const float* prelu   = (const float*)d_in[17];
  const float* fc2_w   = (const float*)d_in[18];
  const float* fc2_b   = (const float*)d_in[19];

  char* base = (char*)d_ws;
  const size_t MB = 1u << 20;
  __bf16* xnb  = (__bf16*)(base + 8 * MB);       // 8-12
  __bf16* qb   = (__bf16*)(base + 12 * MB);      // 12-16  [bh][n][32]
  __bf16* kb   = (__bf16*)(base + 16 * MB);      // 16-20  [bh][n][32]
  __bf16* vt   = (__bf16*)(base + 20 * MB);      // 20-26  [bh][48][1024]
  __bf16* av   = (__bf16*)(base + 30 * MB);      // 30-34
  __bf16* dmc  = (__bf16*)(base + 34 * MB);      // 34-36
  __bf16* xn2b = (__bf16*)(base + 36 * MB);      // 36-40 bf16
  __bf16* hb   = (__bf16*)(base + 12 * MB);      // overlay 12-28 (fc1 out)
  __bf16* qwb  = (__bf16*)(base + 44 * MB);            // 128 KB (q_w)
  __bf16* kvwb = (__bf16*)(base + 44 * MB + 131072);   // 256 KB (kv_w, adj)
  __bf16* pwb  = (__bf16*)(base + 44 * MB + 393216);
  __bf16* mwb  = (__bf16*)(base + 44 * MB + 524288);
  __bf16* f1wb = (__bf16*)(base + 44 * MB + 557056);
  __bf16* f2wb = (__bf16*)(base + 44 * MB + 1081344);
  float*  raw2 = (float*)(base + 45 * MB + 655360);
  float*  st1  = raw2 + 1024;
  float* out0 = (float*)d_out;
  float* out1 = out0 + 2097152;

  (void)hipMemsetAsync(raw2, 0, 512 * sizeof(float), stream);

  prep_k<<<1296, 256, 0, stream>>>(q_w, kv_w, proj_w, mproj_w, fc1_w, fc2_w,
                                   qwb, kvwb, pwb, mwb, f1wb, f2wb,
                                   cor, cor_w, vt, x, g1, b1, st1);
  norm1_t_k<<<dim3(8, 32, 8), dim3(32, 8), 0, stream>>>(x, st1, xnb);

  mgemm_k<1, 128><<<dim3(6, 64), 256, 0, stream>>>(
      xnb, qwb, nullptr, qb, nullptr, kb, vt, 256, 768);

  attn_k<<<dim3(64, 8), 512, 0, stream>>>(qb, kb, vt, cor, cor_w, av, dmc);

  projmot_k<<<dim3(6, 64), 256, 0, stream>>>(av, pwb, proj_b, xn2b, xnb,
                                             dmc, mwb, mproj_b, out1, raw2);

  fc1_k<<<dim3(8, 64), 256, 0, stream>>>(xn2b, raw2, g2, b2, f1wb, fc1_b,
                                         dw_w, dw_b, prelu, hb);

  mgemm_k<5, 64><<<dim3(4, 64), 256, 0, stream>>>(
      hb, f2wb, fc2_b, out0, x, nullptr, nullptr, HID_N, 256);
}

// Round 13
// 101.908 us; speedup vs baseline: 1.2119x; 1.0982x over previous
//
#include <hip/hip_runtime.h>
#include <hip/hip_bf16.h>
#include <math.h>

// MotionFormerBlock: bf16 MFMA GEMMs (BM=64, grid-filling) + swapped-operand
// MFMA flash attn (K-from-global, 128-key steps, defer-max). 8 dispatches.
#define C_DIM 256
#define N_PTS 1024
#define H_N 8
#define MDIM_N 128
#define HID_N 1024
#define EPSV 1e-5f
#define R_TOT 8192
#define CN 262144               // C_DIM * N_PTS

typedef __bf16 bf16x8 __attribute__((ext_vector_type(8)));
typedef __bf16 bf16x4 __attribute__((ext_vector_type(4)));
typedef float f32x4 __attribute__((ext_vector_type(4)));

// softmax scale * log2(e): 32^-0.5 * 1.4426950408889634
#define QSCALE 0.25503482f

__device__ inline unsigned short bfu(float f) {
  union { __bf16 h; unsigned short u; } c;
  c.h = (__bf16)f;
  return c.u;
}

// ---------------------------------------------------- prep: wcvt + cet + bn1
__global__ __launch_bounds__(256)
void prep_k(const float* __restrict__ s0, const float* __restrict__ s1,
            const float* __restrict__ s2, const float* __restrict__ s3,
            const float* __restrict__ s4, const float* __restrict__ s5,
            __bf16* d0, __bf16* d1, __bf16* d2, __bf16* d3, __bf16* d4,
            __bf16* d5, const float* __restrict__ cor,
            const float* __restrict__ cw, __bf16* __restrict__ vt,
            const float* __restrict__ x, const float* __restrict__ g1,
            const float* __restrict__ b1, float* __restrict__ st) {
  int blk = blockIdx.x;
  int t = threadIdx.x;
  if (blk < 784) {
    int i = blk * 256 + t;
    const float* s; __bf16* d; int off;
    if      (i <  16384) { s = s0; d = d0; off = 0; }
    else if (i <  49152) { s = s1; d = d1; off = 16384; }
    else if (i <  65536) { s = s2; d = d2; off = 49152; }
    else if (i <  69632) { s = s3; d = d3; off = 65536; }
    else if (i < 135168) { s = s4; d = d4; off = 69632; }
    else                 { s = s5; d = d5; off = 135168; }
    int j = i - off;
    float4 v = ((const float4*)s)[j];
    ushort4 u;
    u.x = bfu(v.x); u.y = bfu(v.y); u.z = bfu(v.z); u.w = bfu(v.w);
    ((ushort4*)d)[j] = u;
  } else if (blk < 1040) {
    __shared__ float cs[768];
    int j = blk - 784;
    int bh = j & 63, b = bh >> 3, h = bh & 7;
    int n0 = (j >> 6) * 256;
    for (int i = t; i < 768; i += 256)
      cs[i] = cor[(size_t)(b * N_PTS + n0) * 3 + i];
    __syncthreads();
    int md = t >> 4, ns = (t & 15) * 16;
    float w0 = cw[(h * 16 + md) * 3 + 0];
    float w1 = cw[(h * 16 + md) * 3 + 1];
    float w2 = cw[(h * 16 + md) * 3 + 2];
    __bf16* dst = &vt[((size_t)bh * 48 + 32 + md) * 1024 + n0 + ns];
#pragma unroll
    for (int g2 = 0; g2 < 4; ++g2) {
      ushort4 u;
      float v0 = cs[(ns + g2 * 4 + 0) * 3] * w0 + cs[(ns + g2 * 4 + 0) * 3 + 1] * w1 + cs[(ns + g2 * 4 + 0) * 3 + 2] * w2;
      float v1 = cs[(ns + g2 * 4 + 1) * 3] * w0 + cs[(ns + g2 * 4 + 1) * 3 + 1] * w1 + cs[(ns + g2 * 4 + 1) * 3 + 2] * w2;
      float v2 = cs[(ns + g2 * 4 + 2) * 3] * w0 + cs[(ns + g2 * 4 + 2) * 3 + 1] * w1 + cs[(ns + g2 * 4 + 2) * 3 + 2] * w2;
      float v3 = cs[(ns + g2 * 4 + 3) * 3] * w0 + cs[(ns + g2 * 4 + 3) * 3 + 1] * w1 + cs[(ns + g2 * 4 + 3) * 3 + 2] * w2;
      u.x = bfu(v0); u.y = bfu(v1); u.z = bfu(v2); u.w = bfu(v3);
      *(ushort4*)&dst[g2 * 4] = u;
    }
  } else {
    __shared__ float ss[256], sq[256];
    int c = blk - 1040;
    float s = 0.f, q = 0.f;
    for (int i = 0; i < 32; ++i) {
      int idx = t + i * 256;
      int b = idx >> 10, n = idx & 1023;
      float v = x[(size_t)b * CN + (size_t)c * N_PTS + n];
      s += v; q += v * v;
    }
    ss[t] = s; sq[t] = q;
    __syncthreads();
    for (int off = 128; off > 0; off >>= 1) {
      if (t < off) { ss[t] += ss[t + off]; sq[t] += sq[t + off]; }
      __syncthreads();
    }
    if (t == 0) {
      float mean = ss[0] * (1.f / 8192.f);
      float var  = sq[0] * (1.f / 8192.f) - mean * mean;
      float sc   = g1[c] * rsqrtf(var + EPSV);
      st[c]          = sc;
      st[C_DIM + c]  = b1[c] - mean * sc;
    }
  }
}

// ------------------------------------------- normalize + transpose (bf16)
__global__ __launch_bounds__(256)
void norm1_t_k(const float* __restrict__ x, const float* __restrict__ st,
               __bf16* __restrict__ xnb) {
  __shared__ float tile[32][33];
  int c0 = blockIdx.x * 32, n0 = blockIdx.y * 32, b = blockIdx.z;
  int tx = threadIdx.x, ty = threadIdx.y;
#pragma unroll
  for (int k = 0; k < 4; ++k) {
    int ci = ty + k * 8;
    int c = c0 + ci;
    float v = x[(size_t)b * CN + (size_t)c * N_PTS + n0 + tx];
    tile[ci][tx] = v * st[c] + st[C_DIM + c];
  }
  __syncthreads();
#pragma unroll
  for (int k = 0; k < 4; ++k) {
    int ni = ty + k * 8;
    xnb[((size_t)(b * N_PTS + n0 + ni)) * C_DIM + c0 + tx] =
        (__bf16)tile[tx][ni];
  }
}

// ---------------------------------------------------------------- MFMA attention
__global__ __launch_bounds__(512)
void attn_k(const __bf16* __restrict__ qb, const __bf16* __restrict__ kb,
            const __bf16* __restrict__ vt, const float* __restrict__ cor,
            const float* __restrict__ cw, __bf16* __restrict__ av,
            __bf16* __restrict__ dmc) {
  __shared__ __bf16 Vt[2][48][136];   // 26.1 KB
  __shared__ __bf16 Pbuf[8][16][72];  // 18.4 KB

  int bh = blockIdx.x; int b = bh >> 3, h = bh & 7;
  int t = threadIdx.x;
  int w = t >> 6, lane = t & 63;
  int l15 = lane & 15, g = lane >> 4;

  int nloc0 = blockIdx.y * 128 + w * 16;
  bf16x8 aq =
      *(const bf16x8*)&qb[((size_t)bh * N_PTS + nloc0 + l15) * 32 + g * 8];

  const __bf16* ksrc = kb + (size_t)bh * N_PTS * 32;
  const __bf16* vsrc = vt + (size_t)bh * 48 * N_PTS;
  int vdv = t >> 4, vkg = t & 15;

  float mrun = -1e30f, lrun = 0.f;
  f32x4 acco[3];
#pragma unroll
  for (int mt = 0; mt < 3; ++mt) acco[mt] = (f32x4){0.f, 0.f, 0.f, 0.f};

  *(uint4*)&Vt[0][vdv][vkg * 8] =
      *(const uint4*)&vsrc[(size_t)vdv * N_PTS + vkg * 8];
  if (t < 256)
    *(uint4*)&Vt[0][32 + vdv][vkg * 8] =
        *(const uint4*)&vsrc[(size_t)(32 + vdv) * N_PTS + vkg * 8];
  __syncthreads();

  for (int kt = 0; kt < 8; ++kt) {
    int cur = kt & 1, nxt = cur ^ 1;
    uint4 vregA, vregB;
    if (kt < 7) {
      int key1 = (kt + 1) * 128;
      vregA = *(const uint4*)&vsrc[(size_t)vdv * N_PTS + key1 + vkg * 8];
      if (t < 256)
        vregB =
            *(const uint4*)&vsrc[(size_t)(32 + vdv) * N_PTS + key1 + vkg * 8];
    }

    f32x4 sq[8];
    const __bf16* kbase = &ksrc[(size_t)(kt * 128 + l15) * 32 + g * 8];
    __builtin_amdgcn_s_setprio(1);
#pragma unroll
    for (int nt = 0; nt < 8; ++nt) {
      bf16x8 kf = *(const bf16x8*)(kbase + nt * 512);
      f32x4 z = (f32x4){0.f, 0.f, 0.f, 0.f};
      sq[nt] = __builtin_amdgcn_mfma_f32_16x16x32_bf16(kf, aq, z, 0, 0, 0);
    }
    __builtin_amdgcn_s_setprio(0);

    float m0 = fmaxf(fmaxf(sq[0][0], sq[0][1]), fmaxf(sq[0][2], sq[0][3]));
    float m1 = fmaxf(fmaxf(sq[1][0], sq[1][1]), fmaxf(sq[1][2], sq[1][3]));
    float m2 = fmaxf(fmaxf(sq[2][0], sq[2][1]), fmaxf(sq[2][2], sq[2][3]));
    float m3 = fmaxf(fmaxf(sq[3][0], sq[3][1]), fmaxf(sq[3][2], sq[3][3]));
    float m4 = fmaxf(fmaxf(sq[4][0], sq[4][1]), fmaxf(sq[4][2], sq[4][3]));
    float m5 = fmaxf(fmaxf(sq[5][0], sq[5][1]), fmaxf(sq[5][2], sq[5][3]));
    float m6 = fmaxf(fmaxf(sq[6][0], sq[6][1]), fmaxf(sq[6][2], sq[6][3]));
    float m7 = fmaxf(fmaxf(sq[7][0], sq[7][1]), fmaxf(sq[7][2], sq[7][3]));
    float tm = fmaxf(fmaxf(fmaxf(m0, m1), fmaxf(m2, m3)),
                     fmaxf(fmaxf(m4, m5), fmaxf(m6, m7)));
    tm = fmaxf(tm, __shfl_xor(tm, 16));
    tm = fmaxf(tm, __shfl_xor(tm, 32));
    if (__ballot(tm > mrun + 3.0f) != 0ull) {
      float nm = fmaxf(mrun, tm);
      float corr = exp2f(mrun - nm);
      mrun = nm;
      lrun *= corr;
#pragma unroll
      for (int mt = 0; mt < 3; ++mt)
#pragma unroll
        for (int r = 0; r < 4; ++r) acco[mt][r] *= corr;
    }
#pragma unroll
    for (int nt = 0; nt < 8; ++nt)
#pragma unroll
      for (int r = 0; r < 4; ++r) sq[nt][r] = exp2f(sq[nt][r] - mrun);
    float s0 = (sq[0][0] + sq[0][1]) + (sq[0][2] + sq[0][3]);
    float s1 = (sq[1][0] + sq[1][1]) + (sq[1][2] + sq[1][3]);
    float s2 = (sq[2][0] + sq[2][1]) + (sq[2][2] + sq[2][3]);
    float s3 = (sq[3][0] + sq[3][1]) + (sq[3][2] + sq[3][3]);
    float s4 = (sq[4][0] + sq[4][1]) + (sq[4][2] + sq[4][3]);
    float s5 = (sq[5][0] + sq[5][1]) + (sq[5][2] + sq[5][3]);
    float s6 = (sq[6][0] + sq[6][1]) + (sq[6][2] + sq[6][3]);
    float s7 = (sq[7][0] + sq[7][1]) + (sq[7][2] + sq[7][3]);
    float rs = ((s0 + s1) + (s2 + s3)) + ((s4 + s5) + (s6 + s7));
    rs += __shfl_xor(rs, 16);
    rs += __shfl_xor(rs, 32);
    lrun += rs;

#pragma unroll
    for (int half = 0; half < 2; ++half) {
#pragma unroll
      for (int nt2 = 0; nt2 < 4; ++nt2) {
        int nt = half * 4 + nt2;
        bf16x4 pk;
        pk[0] = (__bf16)sq[nt][0]; pk[1] = (__bf16)sq[nt][1];
        pk[2] = (__bf16)sq[nt][2]; pk[3] = (__bf16)sq[nt][3];
        *(bf16x4*)&Pbuf[w][l15][nt2 * 16 + g * 4] = pk;
      }
      bf16x8 ap0 = *(const bf16x8*)&Pbuf[w][l15][g * 8];
      bf16x8 ap1 = *(const bf16x8*)&Pbuf[w][l15][32 + g * 8];
      __builtin_amdgcn_s_setprio(1);
#pragma unroll
      for (int mt = 0; mt < 3; ++mt) {
        bf16x8 vf0 =
            *(const bf16x8*)&Vt[cur][mt * 16 + l15][half * 64 + g * 8];
        acco[mt] =
            __builtin_amdgcn_mfma_f32_16x16x32_bf16(vf0, ap0, acco[mt], 0, 0, 0);
        bf16x8 vf1 =
            *(const bf16x8*)&Vt[cur][mt * 16 + l15][half * 64 + 32 + g * 8];
        acco[mt] =
            __builtin_amdgcn_mfma_f32_16x16x32_bf16(vf1, ap1, acco[mt], 0, 0, 0);
      }
      __builtin_amdgcn_s_setprio(0);
    }

    if (kt < 7) {
      *(uint4*)&Vt[nxt][vdv][vkg * 8] = vregA;
      if (t < 256) *(uint4*)&Vt[nxt][32 + vdv][vkg * 8] = vregB;
      __syncthreads();
    }
  }

  float inv = 1.f / lrun;
  int row = b * N_PTS + nloc0 + l15;
#pragma unroll
  for (int mt = 0; mt < 2; ++mt) {
    ushort4 o;
    o.x = bfu(acco[mt][0] * inv); o.y = bfu(acco[mt][1] * inv);
    o.z = bfu(acco[mt][2] * inv); o.w = bfu(acco[mt][3] * inv);
    *(ushort4*)&av[(size_t)row * C_DIM + h * 32 + mt * 16 + g * 4] = o;
  }
  {
    const float* cp = &cor[(size_t)row * 3];
    float c0 = cp[0], c1 = cp[1], c2 = cp[2];
    ushort4 o;
#pragma unroll
    for (int r = 0; r < 4; ++r) {
      int md = h * 16 + g * 4 + r;
      float ce = c0 * cw[md * 3] + c1 * cw[md * 3 + 1] + c2 * cw[md * 3 + 2];
      float v = acco[2][r] * inv - ce;
      ((unsigned short*)&o)[r] = bfu(v);
    }
    *(ushort4*)&dmc[(size_t)row * MDIM_N + h * 16 + g * 4] = o;
  }
}

// ---------------------------------------------------------------- MFMA GEMM
// 2-barrier single-buffer, templated tile. 4 waves (2x2), wave = BMt/2 x BNt/2.
// MODE 1: fused q+kv (M=768). MODE 5: fc2 transposed residual store.
template <int MODE, int BMt, int BNt>
__global__ __launch_bounds__(256)
void mgemm_k(const __bf16* __restrict__ A, const __bf16* __restrict__ W,
             const float* __restrict__ bias, void* __restrict__ outp,
             const float* __restrict__ e0, __bf16* __restrict__ kbp,
             __bf16* __restrict__ vtp, int K, int M) {
  constexpr int WRW = BMt / 2;
  constexpr int MF = WRW / 16;
  constexpr int WN = BNt / 2;
  constexpr int NR = WN / 16;
  constexpr int APASS = BMt / 32;
  constexpr int BPASS = BNt / 32;
  __shared__ __bf16 Al[BMt * 64];
  __shared__ __bf16 Bl[BNt * 64];
  int t = threadIdx.x;
  int w = t >> 6, lane = t & 63;
  int l15 = lane & 15, g = lane >> 4;
  int wr = w >> 1, wn = w & 1;
  int r0 = blockIdx.y * BMt;
  int m0 = blockIdx.x * BNt;
  bool swapA = (MODE == 1) && (m0 >= 256);

  f32x4 acc[MF][NR];
#pragma unroll
  for (int i = 0; i < MF; ++i)
#pragma unroll
    for (int j = 0; j < NR; ++j) acc[i][j] = (f32x4){0.f, 0.f, 0.f, 0.f};

  for (int kt = 0; kt < K; kt += 64) {
    __syncthreads();
#pragma unroll
    for (int p = 0; p < APASS; ++p) {
      int flat = p * 256 + t;
      int row = flat >> 3, c16 = flat & 7;
      int gr = r0 + row;
      if (swapA) gr = ((((gr >> 10) + 4) & 7) << 10) | (gr & 1023);
      *(uint4*)&Al[row * 64 + (c16 ^ (row & 7)) * 8] =
          *(const uint4*)&A[(size_t)gr * K + kt + c16 * 8];
    }
#pragma unroll
    for (int p = 0; p < BPASS; ++p) {
      int flat = p * 256 + t;
      int row = flat >> 3, c16 = flat & 7;
      *(uint4*)&Bl[row * 64 + (c16 ^ (row & 7)) * 8] =
          *(const uint4*)&W[(size_t)(m0 + row) * K + kt + c16 * 8];
    }
    __syncthreads();
#pragma unroll
    for (int ks = 0; ks < 2; ++ks) {
      bf16x8 af[MF], bf_[NR];
#pragma unroll
      for (int mf = 0; mf < MF; ++mf) {
        int row = wr * WRW + mf * 16 + l15;
        af[mf] = *(const bf16x8*)&Al[row * 64 + ((ks * 4 + g) ^ (l15 & 7)) * 8];
      }
#pragma unroll
      for (int nf = 0; nf < NR; ++nf) {
        int row = wn * WN + nf * 16 + l15;
        bf_[nf] = *(const bf16x8*)&Bl[row * 64 + ((ks * 4 + g) ^ (l15 & 7)) * 8];
      }
#pragma unroll
      for (int mf = 0; mf < MF; ++mf)
#pragma unroll
        for (int nf = 0; nf < NR; ++nf)
          acc[mf][nf] = __builtin_amdgcn_mfma_f32_16x16x32_bf16(
              af[mf], bf_[nf], acc[mf][nf], 0, 0, 0);
    }
  }

#pragma unroll
  for (int mf = 0; mf < MF; ++mf) {
#pragma unroll
    for (int nf = 0; nf < NR; ++nf) {
      int m = m0 + wn * WN + nf * 16 + l15;
      int rbase = r0 + wr * WRW + mf * 16 + g * 4;
      if (MODE == 5) {
        int b = rbase >> 10, n = rbase & 1023;
        size_t oi = (size_t)b * CN + (size_t)m * N_PTS + n;
        float4 xv = *(const float4*)&e0[oi];
        float bs = bias[m];
        float4 ov;
        ov.x = xv.x + acc[mf][nf][0] + bs;
        ov.y = xv.y + acc[mf][nf][1] + bs;
        ov.z = xv.z + acc[mf][nf][2] + bs;
        ov.w = xv.w + acc[mf][nf][3] + bs;
        *(float4*)&((float*)outp)[oi] = ov;
      } else if (MODE == 1 && m0 >= 512) {
        int d = m - 512, hh = d >> 5, dd = d & 31;
        int b = rbase >> 10, n0v = rbase & 1023;
        ushort4 uu;
        uu.x = bfu(acc[mf][nf][0]); uu.y = bfu(acc[mf][nf][1]);
        uu.z = bfu(acc[mf][nf][2]); uu.w = bfu(acc[mf][nf][3]);
        *(ushort4*)&vtp[(((size_t)b * 8 + hh) * 48 + dd) * 1024 + n0v] = uu;
      } else {
#pragma unroll
        for (int r = 0; r < 4; ++r) {
          float v = acc[mf][nf][r];
          int b = rbase >> 10, n = (rbase & 1023) + r;
          if (m0 < 256) {
            int hh = m >> 5, dd = m & 31;
            ((__bf16*)outp)[(((size_t)b * 8 + hh) * 1024 + n) * 32 + dd] =
                (__bf16)(v * QSCALE);
          } else {
            int d = m - 256, hh = d >> 5, dd = d & 31;
            kbp[(((size_t)b * 8 + hh) * 1024 + n) * 32 + dd] = (__bf16)v;
          }
        }
      }
    }
  }
}

// ------------------------------------- proj (+BN2 stats) and motion, fused
// BM=64. blockIdx.x<4: proj; >=4: motion.
__global__ __launch_bounds__(256)
void projmot_k(const __bf16* __restrict__ av, const __bf16* __restrict__ pw,
               const float* __restrict__ pb, __bf16* __restrict__ xn2b,
               const __bf16* __restrict__ xnb, const __bf16* __restrict__ dmc,
               const __bf16* __restrict__ mw, const float* __restrict__ mb,
               float* __restrict__ mot, float* __restrict__ raw2) {
  __shared__ __bf16 Al[64 * 64];
  __shared__ __bf16 Bl[64 * 64];
  bool isProj = blockIdx.x < 4;
  const __bf16* A = isProj ? av : dmc;
  const __bf16* W = isProj ? pw : mw;
  const float* bias = isProj ? pb : mb;
  int K = isProj ? 256 : 128;
  int m0 = (isProj ? blockIdx.x : (blockIdx.x - 4)) * 64;
  int t = threadIdx.x;
  int w = t >> 6, lane = t & 63;
  int l15 = lane & 15, g = lane >> 4;
  int wr = w >> 1, wn = w & 1;
  int r0 = blockIdx.y * 64;

  f32x4 acc[2][2];
#pragma unroll
  for (int i = 0; i < 2; ++i)
#pragma unroll
    for (int j = 0; j < 2; ++j) acc[i][j] = (f32x4){0.f, 0.f, 0.f, 0.f};

  for (int kt = 0; kt < K; kt += 64) {
    __syncthreads();
#pragma unroll
    for (int p = 0; p < 2; ++p) {
      int flat = p * 256 + t;
      int row = flat >> 3, c16 = flat & 7;
      *(uint4*)&Al[row * 64 + (c16 ^ (row & 7)) * 8] =
          *(const uint4*)&A[(size_t)(r0 + row) * K + kt + c16 * 8];
    }
#pragma unroll
    for (int p = 0; p < 2; ++p) {
      int flat = p * 256 + t;
      int row = flat >> 3, c16 = flat & 7;
      *(uint4*)&Bl[row * 64 + (c16 ^ (row & 7)) * 8] =
          *(const uint4*)&W[(size_t)(m0 + row) * K + kt + c16 * 8];
    }
    __syncthreads();
#pragma unroll
    for (int ks = 0; ks < 2; ++ks) {
      bf16x8 af[2], bf_[2];
#pragma unroll
      for (int mf = 0; mf < 2; ++mf) {
        int row = wr * 32 + mf * 16 + l15;
        af[mf] = *(const bf16x8*)&Al[row * 64 + ((ks * 4 + g) ^ (l15 & 7)) * 8];
      }
#pragma unroll
      for (int nf = 0; nf < 2; ++nf) {
        int row = wn * 32 + nf * 16 + l15;
        bf_[nf] = *(const bf16x8*)&Bl[row * 64 + ((ks * 4 + g) ^ (l15 & 7)) * 8];
      }
#pragma unroll
      for (int mf = 0; mf < 2; ++mf)
#pragma unroll
        for (int nf = 0; nf < 2; ++nf)
          acc[mf][nf] = __builtin_amdgcn_mfma_f32_16x16x32_bf16(
              af[mf], bf_[nf], acc[mf][nf], 0, 0, 0);
    }
  }

  float sS[2] = {0.f, 0.f}, sQ[2] = {0.f, 0.f};
#pragma unroll
  for (int mf = 0; mf < 2; ++mf) {
#pragma unroll
    for (int nf = 0; nf < 2; ++nf) {
      int m = m0 + wn * 32 + nf * 16 + l15;
      int rbase = r0 + wr * 32 + mf * 16 + g * 4;
#pragma unroll
      for (int r = 0; r < 4; ++r) {
        float v = acc[mf][nf][r];
        if (isProj) {
          size_t oi = (size_t)(rbase + r) * C_DIM + m;
          float vv = (float)xnb[oi] + v + bias[m];
          xn2b[oi] = (__bf16)vv;
          sS[nf] += vv;
          sQ[nf] += vv * vv;
        } else {
          mot[(size_t)(rbase + r) * MDIM_N + m] = v + bias[m];
        }
      }
    }
  }

  if (isProj) {
    __syncthreads();
    float* colS = (float*)&Al[0];
    float* colQ = colS + 64;
    if (t < 128) colS[t] = 0.f;
    __syncthreads();
#pragma unroll
    for (int nf = 0; nf < 2; ++nf) {
      int mc = wn * 32 + nf * 16 + l15;
      atomicAdd(&colS[mc], sS[nf]);
      atomicAdd(&colQ[mc], sQ[nf]);
    }
    __syncthreads();
    if (t < 64) {
      atomicAdd(&raw2[m0 + t], colS[t]);
      atomicAdd(&raw2[256 + m0 + t], colQ[t]);
    }
  }
}

// ------------------------- fc1: BN2 finalize+apply fused into bf16 A-staging
// BM=64, BN=128.
__global__ __launch_bounds__(256)
void fc1_k(const __bf16* __restrict__ xn2b, const float* __restrict__ raw2,
           const float* __restrict__ g2, const float* __restrict__ b2,
           const __bf16* __restrict__ W, const float* __restrict__ bias,
           const float* __restrict__ dw_w, const float* __restrict__ dw_b,
           const float* __restrict__ pre, __bf16* __restrict__ hb) {
  __shared__ __bf16 Al[64 * 64];
  __shared__ __bf16 Bl[128 * 64];
  __shared__ float scs[256], shs[256];
  int t = threadIdx.x;
  int w = t >> 6, lane = t & 63;
  int l15 = lane & 15, g = lane >> 4;
  int wr = w >> 1, wn = w & 1;
  int r0 = blockIdx.y * 64;
  int m0 = blockIdx.x * 128;

  {
    float mean = raw2[t] * (1.f / 8192.f);
    float var  = raw2[256 + t] * (1.f / 8192.f) - mean * mean;
    float sc   = g2[t] * rsqrtf(var + EPSV);
    scs[t] = sc;
    shs[t] = b2[t] - mean * sc;
  }
  __syncthreads();

  f32x4 acc[2][4];
#pragma unroll
  for (int i = 0; i < 2; ++i)
#pragma unroll
    for (int j = 0; j < 4; ++j) acc[i][j] = (f32x4){0.f, 0.f, 0.f, 0.f};

  for (int kt = 0; kt < 256; kt += 64) {
    __syncthreads();
#pragma unroll
    for (int p = 0; p < 2; ++p) {
      int flat = p * 256 + t;
      int row = flat >> 3, c16 = flat & 7;
      int k = kt + c16 * 8;
      bf16x8 v8 = *(const bf16x8*)&xn2b[(size_t)(r0 + row) * C_DIM + k];
      bf16x8 a;
#pragma unroll
      for (int i = 0; i < 8; ++i)
        a[i] = (__bf16)((float)v8[i] * scs[k + i] + shs[k + i]);
      *(bf16x8*)&Al[row * 64 + (c16 ^ (row & 7)) * 8] = a;
    }
#pragma unroll
    for (int p = 0; p < 4; ++p) {
      int flat = p * 256 + t;
      int row = flat >> 3, c16 = flat & 7;
      *(uint4*)&Bl[row * 64 + (c16 ^ (row & 7)) * 8] =
          *(const uint4*)&W[(size_t)(m0 + row) * 256 + kt + c16 * 8];
    }
    __syncthreads();
#pragma unroll
    for (int ks = 0; ks < 2; ++ks) {
      bf16x8 af[2], bf_[4];
#pragma unroll
      for (int mf = 0; mf < 2; ++mf) {
        int row = wr * 32 + mf * 16 + l15;
        af[mf] = *(const bf16x8*)&Al[row * 64 + ((ks * 4 + g) ^ (l15 & 7)) * 8];
      }
#pragma unroll
      for (int nf = 0; nf < 4; ++nf) {
        int row = wn * 64 + nf * 16 + l15;
        bf_[nf] = *(const bf16x8*)&Bl[row * 64 + ((ks * 4 + g) ^ (l15 & 7)) * 8];
      }
#pragma unroll
      for (int mf = 0; mf < 2; ++mf)
#pragma unroll
        for (int nf = 0; nf < 4; ++nf)
          acc[mf][nf] = __builtin_amdgcn_mfma_f32_16x16x32_bf16(
              af[mf], bf_[nf], acc[mf][nf], 0, 0, 0);
    }
  }

  float a_pre = pre[0];
#pragma unroll
  for (int mf = 0; mf < 2; ++mf) {
#pragma unroll
    for (int nf = 0; nf < 4; ++nf) {
      int m = m0 + wn * 64 + nf * 16 + l15;
      int rbase = r0 + wr * 32 + mf * 16 + g * 4;
      float bs = bias[m], dwm = dw_w[m], dbm = dw_b[m];
#pragma unroll
      for (int r = 0; r < 4; ++r) {
        float v = acc[mf][nf][r] + bs;
        v = v * dwm + dbm;
        hb[(size_t)(rbase + r) * HID_N + m] =
            (__bf16)(v >= 0.f ? v : a_pre * v);
      }
    }
  }
}

extern "C" void kernel_launch(void* const* d_in, const int* in_sizes, int n_in,
                              void* d_out, int out_size, void* d_ws,
                              size_t ws_size, hipStream_t stream) {
  const float* x       = (const float*)d_in[0];
  const float* cor     = (const float*)d_in[1];
  const float* q_w     = (const float*)d_in[2];
  const float* kv_w    = (const float*)d_in[3];
  const float* cor_w   = (const float*)d_in[4];
  const float* proj_w  = (const float*)d_in[5];
  const float* proj_b  = (const float*)d_in[6];
  const float* mproj_w = (const float*)d_in[7];
  const float* mproj_b = (const float*)d_in[8];
  const float* g1      = (const float*)d_in[9];
  const float* b1      = (const float*)d_in[10];
  const float* g2      = (const float*)d_in[11];
  const float* b2      = (const float*)d_in[12];
  const float* fc1_w   = (const float*)d_in[13];
  const float* fc1_b   = (const float*)d_in[14];
  const float* dw_w    = (const float*)d_in[15];
  const float* dw_b    = (const float*)d_in[16];
  const float* prelu   = (const float*)d_in[17];
  const float* fc2_w   = (const float*)d_in[18];
  const float* fc2_b   = (const float*)d_in[19];

  char* base = (char*)d_ws;
  const size_t MB = 1u << 20;
  __bf16* xnb  = (__bf16*)(base + 8 * MB);       // 8-12
  __bf16* qb   = (__bf16*)(base + 12 * MB);      // 12-16  [bh][n][32]
  __bf16* kb   = (__bf16*)(base + 16 * MB);      // 16-20  [bh][n][32]
  __bf16* vt   = (__bf16*)(base + 20 * MB);      // 20-26  [bh][48][1024]
  __bf16* av   = (__bf16*)(base + 30 * MB);      // 30-34
  __bf16* dmc  = (__bf16*)(base + 34 * MB);      // 34-36
  __bf16* xn2b = (__bf16*)(base + 36 * MB);      // 36-40 bf16
  __bf16* hb   = (__bf16*)(base + 12 * MB);      // overlay 12-28 (fc1 out)
  __bf16* qwb  = (__bf16*)(base + 44 * MB);            // 128 KB (q_w)
  __bf16* kvwb = (__bf16*)(base + 44 * MB + 131072);   // 256 KB (kv_w, adj)
  __bf16* pwb  = (__bf16*)(base + 44 * MB + 393216);
  __bf16* mwb  = (__bf16*)(base + 44 * MB + 524288);
  __bf16* f1wb = (__bf16*)(base + 44 * MB + 557056);
  __bf16* f2wb = (__bf16*)(base + 44 * MB + 1081344);
  float*  raw2 = (float*)(base + 45 * MB + 655360);
  float*  st1  = raw2 + 1024;
  float* out0 = (float*)d_out;
  float* out1 = out0 + 2097152;

  (void)hipMemsetAsync(raw2, 0, 512 * sizeof(float), stream);

  prep_k<<<1296, 256, 0, stream>>>(q_w, kv_w, proj_w, mproj_w, fc1_w, fc2_w,
                                   qwb, kvwb, pwb, mwb, f1wb, f2wb,
                                   cor, cor_w, vt, x, g1, b1, st1);
  norm1_t_k<<<dim3(8, 32, 8), dim3(32, 8), 0, stream>>>(x, st1, xnb);

  // fused q+kv GEMM (BM=64): 768 blocks
  mgemm_k<1, 64, 128><<<dim3(6, 128), 256, 0, stream>>>(
      xnb, qwb, nullptr, qb, nullptr, kb, vt, 256, 768);

  attn_k<<<dim3(64, 8), 512, 0, stream>>>(qb, kb, vt, cor, cor_w, av, dmc);

  // proj(+BN2 stats) and motion (BM=64): 768 blocks
  projmot_k<<<dim3(6, 128), 256, 0, stream>>>(av, pwb, proj_b, xn2b, xnb,
                                              dmc, mwb, mproj_b, out1, raw2);

  // fc1 (BM=64, BN=128): 1024 blocks
  fc1_k<<<dim3(8, 128), 256, 0, stream>>>(xn2b, raw2, g2, b2, f1wb, fc1_b,
                                          dw_w, dw_b, prelu, hb);

  // fc2 (BM=64): 512 blocks
  mgemm_k<5, 64, 64><<<dim3(4, 128), 256, 0, stream>>>(
      hb, f2wb, fc2_b, out0, x, nullptr, nullptr, HID_N, 256);
}

// Round 15
// 96.930 us; speedup vs baseline: 1.2741x; 1.0514x over previous
//
#include <hip/hip_runtime.h>
#include <hip/hip_bf16.h>
#include <math.h>

// MotionFormerBlock: bf16 MFMA GEMMs (BM=64, grid-filling) + swapped-operand
// MFMA flash attn (K-from-global, 128-key steps, defer-max). 7 dispatches.
#define C_DIM 256
#define N_PTS 1024
#define H_N 8
#define MDIM_N 128
#define HID_N 1024
#define EPSV 1e-5f
#define R_TOT 8192
#define CN 262144               // C_DIM * N_PTS

typedef __bf16 bf16x8 __attribute__((ext_vector_type(8)));
typedef __bf16 bf16x4 __attribute__((ext_vector_type(4)));
typedef float f32x4 __attribute__((ext_vector_type(4)));

// softmax scale * log2(e): 32^-0.5 * 1.4426950408889634
#define QSCALE 0.25503482f

__device__ inline unsigned short bfu(float f) {
  union { __bf16 h; unsigned short u; } c;
  c.h = (__bf16)f;
  return c.u;
}

// ---------------------------------------------------- prep: wcvt + cet + bn1
// blocks [0,784): weight cvt; [784,1040): ceh->vt; [1040,1296): BN1 stats
// (block 1040 also zeroes raw2 — replaces the memset dispatch).
__global__ __launch_bounds__(256)
void prep_k(const float* __restrict__ s0, const float* __restrict__ s1,
            const float* __restrict__ s2, const float* __restrict__ s3,
            const float* __restrict__ s4, const float* __restrict__ s5,
            __bf16* d0, __bf16* d1, __bf16* d2, __bf16* d3, __bf16* d4,
            __bf16* d5, const float* __restrict__ cor,
            const float* __restrict__ cw, __bf16* __restrict__ vt,
            const float* __restrict__ x, const float* __restrict__ g1,
            const float* __restrict__ b1, float* __restrict__ st,
            float* __restrict__ raw2) {
  int blk = blockIdx.x;
  int t = threadIdx.x;
  if (blk < 784) {
    int i = blk * 256 + t;
    const float* s; __bf16* d; int off;
    if      (i <  16384) { s = s0; d = d0; off = 0; }
    else if (i <  49152) { s = s1; d = d1; off = 16384; }
    else if (i <  65536) { s = s2; d = d2; off = 49152; }
    else if (i <  69632) { s = s3; d = d3; off = 65536; }
    else if (i < 135168) { s = s4; d = d4; off = 69632; }
    else                 { s = s5; d = d5; off = 135168; }
    int j = i - off;
    float4 v = ((const float4*)s)[j];
    ushort4 u;
    u.x = bfu(v.x); u.y = bfu(v.y); u.z = bfu(v.z); u.w = bfu(v.w);
    ((ushort4*)d)[j] = u;
  } else if (blk < 1040) {
    __shared__ float cs[768];
    int j = blk - 784;
    int bh = j & 63, b = bh >> 3, h = bh & 7;
    int n0 = (j >> 6) * 256;
    for (int i = t; i < 768; i += 256)
      cs[i] = cor[(size_t)(b * N_PTS + n0) * 3 + i];
    __syncthreads();
    int md = t >> 4, ns = (t & 15) * 16;
    float w0 = cw[(h * 16 + md) * 3 + 0];
    float w1 = cw[(h * 16 + md) * 3 + 1];
    float w2 = cw[(h * 16 + md) * 3 + 2];
    __bf16* dst = &vt[((size_t)bh * 48 + 32 + md) * 1024 + n0 + ns];
#pragma unroll
    for (int g2 = 0; g2 < 4; ++g2) {
      ushort4 u;
      float v0 = cs[(ns + g2 * 4 + 0) * 3] * w0 + cs[(ns + g2 * 4 + 0) * 3 + 1] * w1 + cs[(ns + g2 * 4 + 0) * 3 + 2] * w2;
      float v1 = cs[(ns + g2 * 4 + 1) * 3] * w0 + cs[(ns + g2 * 4 + 1) * 3 + 1] * w1 + cs[(ns + g2 * 4 + 1) * 3 + 2] * w2;
      float v2 = cs[(ns + g2 * 4 + 2) * 3] * w0 + cs[(ns + g2 * 4 + 2) * 3 + 1] * w1 + cs[(ns + g2 * 4 + 2) * 3 + 2] * w2;
      float v3 = cs[(ns + g2 * 4 + 3) * 3] * w0 + cs[(ns + g2 * 4 + 3) * 3 + 1] * w1 + cs[(ns + g2 * 4 + 3) * 3 + 2] * w2;
      u.x = bfu(v0); u.y = bfu(v1); u.z = bfu(v2); u.w = bfu(v3);
      *(ushort4*)&dst[g2 * 4] = u;
    }
  } else {
    __shared__ float ss[256], sq[256];
    int c = blk - 1040;
    if (blk == 1040) { raw2[t] = 0.f; raw2[256 + t] = 0.f; }
    float s = 0.f, q = 0.f;
    for (int i = 0; i < 32; ++i) {
      int idx = t + i * 256;
      int b = idx >> 10, n = idx & 1023;
      float v = x[(size_t)b * CN + (size_t)c * N_PTS + n];
      s += v; q += v * v;
    }
    ss[t] = s; sq[t] = q;
    __syncthreads();
    for (int off = 128; off > 0; off >>= 1) {
      if (t < off) { ss[t] += ss[t + off]; sq[t] += sq[t + off]; }
      __syncthreads();
    }
    if (t == 0) {
      float mean = ss[0] * (1.f / 8192.f);
      float var  = sq[0] * (1.f / 8192.f) - mean * mean;
      float sc   = g1[c] * rsqrtf(var + EPSV);
      st[c]          = sc;
      st[C_DIM + c]  = b1[c] - mean * sc;
    }
  }
}

// ------------------------------------------- normalize + transpose (bf16)
__global__ __launch_bounds__(256)
void norm1_t_k(const float* __restrict__ x, const float* __restrict__ st,
               __bf16* __restrict__ xnb) {
  __shared__ float tile[32][33];
  int c0 = blockIdx.x * 32, n0 = blockIdx.y * 32, b = blockIdx.z;
  int tx = threadIdx.x, ty = threadIdx.y;
#pragma unroll
  for (int k = 0; k < 4; ++k) {
    int ci = ty + k * 8;
    int c = c0 + ci;
    float v = x[(size_t)b * CN + (size_t)c * N_PTS + n0 + tx];
    tile[ci][tx] = v * st[c] + st[C_DIM + c];
  }
  __syncthreads();
#pragma unroll
  for (int k = 0; k < 4; ++k) {
    int ni = ty + k * 8;
    xnb[((size_t)(b * N_PTS + n0 + ni)) * C_DIM + c0 + tx] =
        (__bf16)tile[tx][ni];
  }
}

// ---------------------------------------------------------------- MFMA attention
__global__ __launch_bounds__(512)
void attn_k(const __bf16* __restrict__ qb, const __bf16* __restrict__ kb,
            const __bf16* __restrict__ vt, const float* __restrict__ cor,
            const float* __restrict__ cw, __bf16* __restrict__ av,
            __bf16* __restrict__ dmc) {
  __shared__ __bf16 Vt[2][48][136];   // 26.1 KB
  __shared__ __bf16 Pbuf[8][16][72];  // 18.4 KB

  int bh = blockIdx.x; int b = bh >> 3, h = bh & 7;
  int t = threadIdx.x;
  int w = t >> 6, lane = t & 63;
  int l15 = lane & 15, g = lane >> 4;

  int nloc0 = blockIdx.y * 128 + w * 16;
  bf16x8 aq =
      *(const bf16x8*)&qb[((size_t)bh * N_PTS + nloc0 + l15) * 32 + g * 8];

  const __bf16* ksrc = kb + (size_t)bh * N_PTS * 32;
  const __bf16* vsrc = vt + (size_t)bh * 48 * N_PTS;
  int vdv = t >> 4, vkg = t & 15;

  float mrun = -1e30f, lrun = 0.f;
  f32x4 acco[3];
#pragma unroll
  for (int mt = 0; mt < 3; ++mt) acco[mt] = (f32x4){0.f, 0.f, 0.f, 0.f};

  *(uint4*)&Vt[0][vdv][vkg * 8] =
      *(const uint4*)&vsrc[(size_t)vdv * N_PTS + vkg * 8];
  if (t < 256)
    *(uint4*)&Vt[0][32 + vdv][vkg * 8] =
        *(const uint4*)&vsrc[(size_t)(32 + vdv) * N_PTS + vkg * 8];
  __syncthreads();

  for (int kt = 0; kt < 8; ++kt) {
    int cur = kt & 1, nxt = cur ^ 1;
    uint4 vregA, vregB;
    if (kt < 7) {
      int key1 = (kt + 1) * 128;
      vregA = *(const uint4*)&vsrc[(size_t)vdv * N_PTS + key1 + vkg * 8];
      if (t < 256)
        vregB =
            *(const uint4*)&vsrc[(size_t)(32 + vdv) * N_PTS + key1 + vkg * 8];
    }

    f32x4 sq[8];
    const __bf16* kbase = &ksrc[(size_t)(kt * 128 + l15) * 32 + g * 8];
    __builtin_amdgcn_s_setprio(1);
#pragma unroll
    for (int nt = 0; nt < 8; ++nt) {
      bf16x8 kf = *(const bf16x8*)(kbase + nt * 512);
      f32x4 z = (f32x4){0.f, 0.f, 0.f, 0.f};
      sq[nt] = __builtin_amdgcn_mfma_f32_16x16x32_bf16(kf, aq, z, 0, 0, 0);
    }
    __builtin_amdgcn_s_setprio(0);

    float m0 = fmaxf(fmaxf(sq[0][0], sq[0][1]), fmaxf(sq[0][2], sq[0][3]));
    float m1 = fmaxf(fmaxf(sq[1][0], sq[1][1]), fmaxf(sq[1][2], sq[1][3]));
    float m2 = fmaxf(fmaxf(sq[2][0], sq[2][1]), fmaxf(sq[2][2], sq[2][3]));
    float m3 = fmaxf(fmaxf(sq[3][0], sq[3][1]), fmaxf(sq[3][2], sq[3][3]));
    float m4 = fmaxf(fmaxf(sq[4][0], sq[4][1]), fmaxf(sq[4][2], sq[4][3]));
    float m5 = fmaxf(fmaxf(sq[5][0], sq[5][1]), fmaxf(sq[5][2], sq[5][3]));
    float m6 = fmaxf(fmaxf(sq[6][0], sq[6][1]), fmaxf(sq[6][2], sq[6][3]));
    float m7 = fmaxf(fmaxf(sq[7][0], sq[7][1]), fmaxf(sq[7][2], sq[7][3]));
    float tm = fmaxf(fmaxf(fmaxf(m0, m1), fmaxf(m2, m3)),
                     fmaxf(fmaxf(m4, m5), fmaxf(m6, m7)));
    tm = fmaxf(tm, __shfl_xor(tm, 16));
    tm = fmaxf(tm, __shfl_xor(tm, 32));
    if (__ballot(tm > mrun + 3.0f) != 0ull) {
      float nm = fmaxf(mrun, tm);
      float corr = exp2f(mrun - nm);
      mrun = nm;
      lrun *= corr;
#pragma unroll
      for (int mt = 0; mt < 3; ++mt)
#pragma unroll
        for (int r = 0; r < 4; ++r) acco[mt][r] *= corr;
    }
#pragma unroll
    for (int nt = 0; nt < 8; ++nt)
#pragma unroll
      for (int r = 0; r < 4; ++r) sq[nt][r] = exp2f(sq[nt][r] - mrun);
    float s0 = (sq[0][0] + sq[0][1]) + (sq[0][2] + sq[0][3]);
    float s1 = (sq[1][0] + sq[1][1]) + (sq[1][2] + sq[1][3]);
    float s2 = (sq[2][0] + sq[2][1]) + (sq[2][2] + sq[2][3]);
    float s3 = (sq[3][0] + sq[3][1]) + (sq[3][2] + sq[3][3]);
    float s4 = (sq[4][0] + sq[4][1]) + (sq[4][2] + sq[4][3]);
    float s5 = (sq[5][0] + sq[5][1]) + (sq[5][2] + sq[5][3]);
    float s6 = (sq[6][0] + sq[6][1]) + (sq[6][2] + sq[6][3]);
    float s7 = (sq[7][0] + sq[7][1]) + (sq[7][2] + sq[7][3]);
    float rs = ((s0 + s1) + (s2 + s3)) + ((s4 + s5) + (s6 + s7));
    rs += __shfl_xor(rs, 16);
    rs += __shfl_xor(rs, 32);
    lrun += rs;

#pragma unroll
    for (int half = 0; half < 2; ++half) {
#pragma unroll
      for (int nt2 = 0; nt2 < 4; ++nt2) {
        int nt = half * 4 + nt2;
        bf16x4 pk;
        pk[0] = (__bf16)sq[nt][0]; pk[1] = (__bf16)sq[nt][1];
        pk[2] = (__bf16)sq[nt][2]; pk[3] = (__bf16)sq[nt][3];
        *(bf16x4*)&Pbuf[w][l15][nt2 * 16 + g * 4] = pk;
      }
      bf16x8 ap0 = *(const bf16x8*)&Pbuf[w][l15][g * 8];
      bf16x8 ap1 = *(const bf16x8*)&Pbuf[w][l15][32 + g * 8];
      __builtin_amdgcn_s_setprio(1);
#pragma unroll
      for (int mt = 0; mt < 3; ++mt) {
        bf16x8 vf0 =
            *(const bf16x8*)&Vt[cur][mt * 16 + l15][half * 64 + g * 8];
        acco[mt] =
            __builtin_amdgcn_mfma_f32_16x16x32_bf16(vf0, ap0, acco[mt], 0, 0, 0);
        bf16x8 vf1 =
            *(const bf16x8*)&Vt[cur][mt * 16 + l15][half * 64 + 32 + g * 8];
        acco[mt] =
            __builtin_amdgcn_mfma_f32_16x16x32_bf16(vf1, ap1, acco[mt], 0, 0, 0);
      }
      __builtin_amdgcn_s_setprio(0);
    }

    if (kt < 7) {
      *(uint4*)&Vt[nxt][vdv][vkg * 8] = vregA;
      if (t < 256) *(uint4*)&Vt[nxt][32 + vdv][vkg * 8] = vregB;
      __syncthreads();
    }
  }

  float inv = 1.f / lrun;
  int row = b * N_PTS + nloc0 + l15;
#pragma unroll
  for (int mt = 0; mt < 2; ++mt) {
    ushort4 o;
    o.x = bfu(acco[mt][0] * inv); o.y = bfu(acco[mt][1] * inv);
    o.z = bfu(acco[mt][2] * inv); o.w = bfu(acco[mt][3] * inv);
    *(ushort4*)&av[(size_t)row * C_DIM + h * 32 + mt * 16 + g * 4] = o;
  }
  {
    const float* cp = &cor[(size_t)row * 3];
    float c0 = cp[0], c1 = cp[1], c2 = cp[2];
    ushort4 o;
#pragma unroll
    for (int r = 0; r < 4; ++r) {
      int md = h * 16 + g * 4 + r;
      float ce = c0 * cw[md * 3] + c1 * cw[md * 3 + 1] + c2 * cw[md * 3 + 2];
      float v = acco[2][r] * inv - ce;
      ((unsigned short*)&o)[r] = bfu(v);
    }
    *(ushort4*)&dmc[(size_t)row * MDIM_N + h * 16 + g * 4] = o;
  }
}

// ---------------------------------------------------------------- MFMA GEMM
// 2-barrier single-buffer, templated tile. 4 waves (2x2), wave = BMt/2 x BNt/2.
// MODE 1: fused q+kv (M=768). MODE 5: fc2 transposed residual store.
template <int MODE, int BMt, int BNt>
__global__ __launch_bounds__(256)
void mgemm_k(const __bf16* __restrict__ A, const __bf16* __restrict__ W,
             const float* __restrict__ bias, void* __restrict__ outp,
             const float* __restrict__ e0, __bf16* __restrict__ kbp,
             __bf16* __restrict__ vtp, int K, int M) {
  constexpr int WRW = BMt / 2;
  constexpr int MF = WRW / 16;
  constexpr int WN = BNt / 2;
  constexpr int NR = WN / 16;
  constexpr int APASS = BMt / 32;
  constexpr int BPASS = BNt / 32;
  __shared__ __bf16 Al[BMt * 64];
  __shared__ __bf16 Bl[BNt * 64];
  int t = threadIdx.x;
  int w = t >> 6, lane = t & 63;
  int l15 = lane & 15, g = lane >> 4;
  int wr = w >> 1, wn = w & 1;
  int r0 = blockIdx.y * BMt;
  int m0 = blockIdx.x * BNt;
  bool swapA = (MODE == 1) && (m0 >= 256);

  f32x4 acc[MF][NR];
#pragma unroll
  for (int i = 0; i < MF; ++i)
#pragma unroll
    for (int j = 0; j < NR; ++j) acc[i][j] = (f32x4){0.f, 0.f, 0.f, 0.f};

  for (int kt = 0; kt < K; kt += 64) {
    __syncthreads();
#pragma unroll
    for (int p = 0; p < APASS; ++p) {
      int flat = p * 256 + t;
      int row = flat >> 3, c16 = flat & 7;
      int gr = r0 + row;
      if (swapA) gr = ((((gr >> 10) + 4) & 7) << 10) | (gr & 1023);
      *(uint4*)&Al[row * 64 + (c16 ^ (row & 7)) * 8] =
          *(const uint4*)&A[(size_t)gr * K + kt + c16 * 8];
    }
#pragma unroll
    for (int p = 0; p < BPASS; ++p) {
      int flat = p * 256 + t;
      int row = flat >> 3, c16 = flat & 7;
      *(uint4*)&Bl[row * 64 + (c16 ^ (row & 7)) * 8] =
          *(const uint4*)&W[(size_t)(m0 + row) * K + kt + c16 * 8];
    }
    __syncthreads();
#pragma unroll
    for (int ks = 0; ks < 2; ++ks) {
      bf16x8 af[MF], bf_[NR];
#pragma unroll
      for (int mf = 0; mf < MF; ++mf) {
        int row = wr * WRW + mf * 16 + l15;
        af[mf] = *(const bf16x8*)&Al[row * 64 + ((ks * 4 + g) ^ (l15 & 7)) * 8];
      }
#pragma unroll
      for (int nf = 0; nf < NR; ++nf) {
        int row = wn * WN + nf * 16 + l15;
        bf_[nf] = *(const bf16x8*)&Bl[row * 64 + ((ks * 4 + g) ^ (l15 & 7)) * 8];
      }
#pragma unroll
      for (int mf = 0; mf < MF; ++mf)
#pragma unroll
        for (int nf = 0; nf < NR; ++nf)
          acc[mf][nf] = __builtin_amdgcn_mfma_f32_16x16x32_bf16(
              af[mf], bf_[nf], acc[mf][nf], 0, 0, 0);
    }
  }

#pragma unroll
  for (int mf = 0; mf < MF; ++mf) {
#pragma unroll
    for (int nf = 0; nf < NR; ++nf) {
      int m = m0 + wn * WN + nf * 16 + l15;
      int rbase = r0 + wr * WRW + mf * 16 + g * 4;
      if (MODE == 5) {
        int b = rbase >> 10, n = rbase & 1023;
        size_t oi = (size_t)b * CN + (size_t)m * N_PTS + n;
        float4 xv = *(const float4*)&e0[oi];
        float bs = bias[m];
        float4 ov;
        ov.x = xv.x + acc[mf][nf][0] + bs;
        ov.y = xv.y + acc[mf][nf][1] + bs;
        ov.z = xv.z + acc[mf][nf][2] + bs;
        ov.w = xv.w + acc[mf][nf][3] + bs;
        *(float4*)&((float*)outp)[oi] = ov;
      } else if (MODE == 1 && m0 >= 512) {
        int d = m - 512, hh = d >> 5, dd = d & 31;
        int b = rbase >> 10, n0v = rbase & 1023;
        ushort4 uu;
        uu.x = bfu(acc[mf][nf][0]); uu.y = bfu(acc[mf][nf][1]);
        uu.z = bfu(acc[mf][nf][2]); uu.w = bfu(acc[mf][nf][3]);
        *(ushort4*)&vtp[(((size_t)b * 8 + hh) * 48 + dd) * 1024 + n0v] = uu;
      } else {
#pragma unroll
        for (int r = 0; r < 4; ++r) {
          float v = acc[mf][nf][r];
          int b = rbase >> 10, n = (rbase & 1023) + r;
          if (m0 < 256) {
            int hh = m >> 5, dd = m & 31;
            ((__bf16*)outp)[(((size_t)b * 8 + hh) * 1024 + n) * 32 + dd] =
                (__bf16)(v * QSCALE);
          } else {
            int d = m - 256, hh = d >> 5, dd = d & 31;
            kbp[(((size_t)b * 8 + hh) * 1024 + n) * 32 + dd] = (__bf16)v;
          }
        }
      }
    }
  }
}

// ------------------------------------- proj (+BN2 stats) and motion, fused
// BM=64. blockIdx.x<4: proj; >=4: motion.
__global__ __launch_bounds__(256)
void projmot_k(const __bf16* __restrict__ av, const __bf16* __restrict__ pw,
               const float* __restrict__ pb, __bf16* __restrict__ xn2b,
               const __bf16* __restrict__ xnb, const __bf16* __restrict__ dmc,
               const __bf16* __restrict__ mw, const float* __restrict__ mb,
               float* __restrict__ mot, float* __restrict__ raw2) {
  __shared__ __bf16 Al[64 * 64];
  __shared__ __bf16 Bl[64 * 64];
  bool isProj = blockIdx.x < 4;
  const __bf16* A = isProj ? av : dmc;
  const __bf16* W = isProj ? pw : mw;
  const float* bias = isProj ? pb : mb;
  int K = isProj ? 256 : 128;
  int m0 = (isProj ? blockIdx.x : (blockIdx.x - 4)) * 64;
  int t = threadIdx.x;
  int w = t >> 6, lane = t & 63;
  int l15 = lane & 15, g = lane >> 4;
  int wr = w >> 1, wn = w & 1;
  int r0 = blockIdx.y * 64;

  f32x4 acc[2][2];
#pragma unroll
  for (int i = 0; i < 2; ++i)
#pragma unroll
    for (int j = 0; j < 2; ++j) acc[i][j] = (f32x4){0.f, 0.f, 0.f, 0.f};

  for (int kt = 0; kt < K; kt += 64) {
    __syncthreads();
#pragma unroll
    for (int p = 0; p < 2; ++p) {
      int flat = p * 256 + t;
      int row = flat >> 3, c16 = flat & 7;
      *(uint4*)&Al[row * 64 + (c16 ^ (row & 7)) * 8] =
          *(const uint4*)&A[(size_t)(r0 + row) * K + kt + c16 * 8];
    }
#pragma unroll
    for (int p = 0; p < 2; ++p) {
      int flat = p * 256 + t;
      int row = flat >> 3, c16 = flat & 7;
      *(uint4*)&Bl[row * 64 + (c16 ^ (row & 7)) * 8] =
          *(const uint4*)&W[(size_t)(m0 + row) * K + kt + c16 * 8];
    }
    __syncthreads();
#pragma unroll
    for (int ks = 0; ks < 2; ++ks) {
      bf16x8 af[2], bf_[2];
#pragma unroll
      for (int mf = 0; mf < 2; ++mf) {
        int row = wr * 32 + mf * 16 + l15;
        af[mf] = *(const bf16x8*)&Al[row * 64 + ((ks * 4 + g) ^ (l15 & 7)) * 8];
      }
#pragma unroll
      for (int nf = 0; nf < 2; ++nf) {
        int row = wn * 32 + nf * 16 + l15;
        bf_[nf] = *(const bf16x8*)&Bl[row * 64 + ((ks * 4 + g) ^ (l15 & 7)) * 8];
      }
#pragma unroll
      for (int mf = 0; mf < 2; ++mf)
#pragma unroll
        for (int nf = 0; nf < 2; ++nf)
          acc[mf][nf] = __builtin_amdgcn_mfma_f32_16x16x32_bf16(
              af[mf], bf_[nf], acc[mf][nf], 0, 0, 0);
    }
  }

  float sS[2] = {0.f, 0.f}, sQ[2] = {0.f, 0.f};
#pragma unroll
  for (int mf = 0; mf < 2; ++mf) {
#pragma unroll
    for (int nf = 0; nf < 2; ++nf) {
      int m = m0 + wn * 32 + nf * 16 + l15;
      int rbase = r0 + wr * 32 + mf * 16 + g * 4;
#pragma unroll
      for (int r = 0; r < 4; ++r) {
        float v = acc[mf][nf][r];
        if (isProj) {
          size_t oi = (size_t)(rbase + r) * C_DIM + m;
          float vv = (float)xnb[oi] + v + bias[m];
          xn2b[oi] = (__bf16)vv;
          sS[nf] += vv;
          sQ[nf] += vv * vv;
        } else {
          mot[(size_t)(rbase + r) * MDIM_N + m] = v + bias[m];
        }
      }
    }
  }

  if (isProj) {
    __syncthreads();
    float* colS = (float*)&Al[0];
    float* colQ = colS + 64;
    if (t < 128) colS[t] = 0.f;
    __syncthreads();
#pragma unroll
    for (int nf = 0; nf < 2; ++nf) {
      int mc = wn * 32 + nf * 16 + l15;
      atomicAdd(&colS[mc], sS[nf]);
      atomicAdd(&colQ[mc], sQ[nf]);
    }
    __syncthreads();
    if (t < 64) {
      atomicAdd(&raw2[m0 + t], colS[t]);
      atomicAdd(&raw2[256 + m0 + t], colQ[t]);
    }
  }
}

// ------------------------- fc1: BN2 finalize+apply fused into bf16 A-staging
// BM=64, BN=128.
__global__ __launch_bounds__(256)
void fc1_k(const __bf16* __restrict__ xn2b, const float* __restrict__ raw2,
           const float* __restrict__ g2, const float* __restrict__ b2,
           const __bf16* __restrict__ W, const float* __restrict__ bias,
           const float* __restrict__ dw_w, const float* __restrict__ dw_b,
           const float* __restrict__ pre, __bf16* __restrict__ hb) {
  __shared__ __bf16 Al[64 * 64];
  __shared__ __bf16 Bl[128 * 64];
  __shared__ float scs[256], shs[256];
  int t = threadIdx.x;
  int w = t >> 6, lane = t & 63;
  int l15 = lane & 15, g = lane >> 4;
  int wr = w >> 1, wn = w & 1;
  int r0 = blockIdx.y * 64;
  int m0 = blockIdx.x * 128;

  {
    float mean = raw2[t] * (1.f / 8192.f);
    float var  = raw2[256 + t] * (1.f / 8192.f) - mean * mean;
    float sc   = g2[t] * rsqrtf(var + EPSV);
    scs[t] = sc;
    shs[t] = b2[t] - mean * sc;
  }
  __syncthreads();

  f32x4 acc[2][4];
#pragma unroll
  for (int i = 0; i < 2; ++i)
#pragma unroll
    for (int j = 0; j < 4; ++j) acc[i][j] = (f32x4){0.f, 0.f, 0.f, 0.f};

  for (int kt = 0; kt < 256; kt += 64) {
    __syncthreads();
#pragma unroll
    for (int p = 0; p < 2; ++p) {
      int flat = p * 256 + t;
      int row = flat >> 3, c16 = flat & 7;
      int k = kt + c16 * 8;
      bf16x8 v8 = *(const bf16x8*)&xn2b[(size_t)(r0 + row) * C_DIM + k];
      bf16x8 a;
#pragma unroll
      for (int i = 0; i < 8; ++i)
        a[i] = (__bf16)((float)v8[i] * scs[k + i] + shs[k + i]);
      *(bf16x8*)&Al[row * 64 + (c16 ^ (row & 7)) * 8] = a;
    }
#pragma unroll
    for (int p = 0; p < 4; ++p) {
      int flat = p * 256 + t;
      int row = flat >> 3, c16 = flat & 7;
      *(uint4*)&Bl[row * 64 + (c16 ^ (row & 7)) * 8] =
          *(const uint4*)&W[(size_t)(m0 + row) * 256 + kt + c16 * 8];
    }
    __syncthreads();
#pragma unroll
    for (int ks = 0; ks < 2; ++ks) {
      bf16x8 af[2], bf_[4];
#pragma unroll
      for (int mf = 0; mf < 2; ++mf) {
        int row = wr * 32 + mf * 16 + l15;
        af[mf] = *(const bf16x8*)&Al[row * 64 + ((ks * 4 + g) ^ (l15 & 7)) * 8];
      }
#pragma unroll
      for (int nf = 0; nf < 4; ++nf) {
        int row = wn * 64 + nf * 16 + l15;
        bf_[nf] = *(const bf16x8*)&Bl[row * 64 + ((ks * 4 + g) ^ (l15 & 7)) * 8];
      }
#pragma unroll
      for (int mf = 0; mf < 2; ++mf)
#pragma unroll
        for (int nf = 0; nf < 4; ++nf)
          acc[mf][nf] = __builtin_amdgcn_mfma_f32_16x16x32_bf16(
              af[mf], bf_[nf], acc[mf][nf], 0, 0, 0);
    }
  }

  float a_pre = pre[0];
#pragma unroll
  for (int mf = 0; mf < 2; ++mf) {
#pragma unroll
    for (int nf = 0; nf < 4; ++nf) {
      int m = m0 + wn * 64 + nf * 16 + l15;
      int rbase = r0 + wr * 32 + mf * 16 + g * 4;
      float bs = bias[m], dwm = dw_w[m], dbm = dw_b[m];
#pragma unroll
      for (int r = 0; r < 4; ++r) {
        float v = acc[mf][nf][r] + bs;
        v = v * dwm + dbm;
        hb[(size_t)(rbase + r) * HID_N + m] =
            (__bf16)(v >= 0.f ? v : a_pre * v);
      }
    }
  }
}

extern "C" void kernel_launch(void* const* d_in, const int* in_sizes, int n_in,
                              void* d_out, int out_size, void* d_ws,
                              size_t ws_size, hipStream_t stream) {
  const float* x       = (const float*)d_in[0];
  const float* cor     = (const float*)d_in[1];
  const float* q_w     = (const float*)d_in[2];
  const float* kv_w    = (const float*)d_in[3];
  const float* cor_w   = (const float*)d_in[4];
  const float* proj_w  = (const float*)d_in[5];
  const float* proj_b  = (const float*)d_in[6];
  const float* mproj_w = (const float*)d_in[7];
  const float* mproj_b = (const float*)d_in[8];
  const float* g1      = (const float*)d_in[9];
  const float* b1      = (const float*)d_in[10];
  const float* g2      = (const float*)d_in[11];
  const float* b2      = (const float*)d_in[12];
  const float* fc1_w   = (const float*)d_in[13];
  const float* fc1_b   = (const float*)d_in[14];
  const float* dw_w    = (const float*)d_in[15];
  const float* dw_b    = (const float*)d_in[16];
  const float* prelu   = (const float*)d_in[17];
  const float* fc2_w   = (const float*)d_in[18];
  const float* fc2_b   = (const float*)d_in[19];

  char* base = (char*)d_ws;
  const size_t MB = 1u << 20;
  __bf16* xnb  = (__bf16*)(base + 8 * MB);       // 8-12
  __bf16* qb   = (__bf16*)(base + 12 * MB);      // 12-16  [bh][n][32]
  __bf16* kb   = (__bf16*)(base + 16 * MB);      // 16-20  [bh][n][32]
  __bf16* vt   = (__bf16*)(base + 20 * MB);      // 20-26  [bh][48][1024]
  __bf16* av   = (__bf16*)(base + 30 * MB);      // 30-34
  __bf16* dmc  = (__bf16*)(base + 34 * MB);      // 34-36
  __bf16* xn2b = (__bf16*)(base + 36 * MB);      // 36-40 bf16
  __bf16* hb   = (__bf16*)(base + 12 * MB);      // overlay 12-28 (fc1 out)
  __bf16* qwb  = (__bf16*)(base + 44 * MB);            // 128 KB (q_w)
  __bf16* kvwb = (__bf16*)(base + 44 * MB + 131072);   // 256 KB (kv_w, adj)
  __bf16* pwb  = (__bf16*)(base + 44 * MB + 393216);
  __bf16* mwb  = (__bf16*)(base + 44 * MB + 524288);
  __bf16* f1wb = (__bf16*)(base + 44 * MB + 557056);
  __bf16* f2wb = (__bf16*)(base + 44 * MB + 1081344);
  float*  raw2 = (float*)(base + 45 * MB + 655360);
  float*  st1  = raw2 + 1024;
  float* out0 = (float*)d_out;
  float* out1 = out0 + 2097152;

  prep_k<<<1296, 256, 0, stream>>>(q_w, kv_w, proj_w, mproj_w, fc1_w, fc2_w,
                                   qwb, kvwb, pwb, mwb, f1wb, f2wb,
                                   cor, cor_w, vt, x, g1, b1, st1, raw2);
  norm1_t_k<<<dim3(8, 32, 8), dim3(32, 8), 0, stream>>>(x, st1, xnb);

  // fused q+kv GEMM (BM=64): 768 blocks
  mgemm_k<1, 64, 128><<<dim3(6, 128), 256, 0, stream>>>(
      xnb, qwb, nullptr, qb, nullptr, kb, vt, 256, 768);

  attn_k<<<dim3(64, 8), 512, 0, stream>>>(qb, kb, vt, cor, cor_w, av, dmc);

  // proj(+BN2 stats) and motion (BM=64): 768 blocks
  projmot_k<<<dim3(6, 128), 256, 0, stream>>>(av, pwb, proj_b, xn2b, xnb,
                                              dmc, mwb, mproj_b, out1, raw2);

  // fc1 (BM=64, BN=128): 1024 blocks
  fc1_k<<<dim3(8, 128), 256, 0, stream>>>(xn2b, raw2, g2, b2, f1wb, fc1_b,
                                          dw_w, dw_b, prelu, hb);

  // fc2 (BM=64): 512 blocks
  mgemm_k<5, 64, 64><<<dim3(4, 128), 256, 0, stream>>>(
      hb, f2wb, fc2_b, out0, x, nullptr, nullptr, HID_N, 256);
}